// Round 4
// baseline (1910.789 us; speedup 1.0000x reference)
//
#include <hip/hip_runtime.h>
#include <hip/hip_bf16.h>

#define DIM    1024
#define HEADS  16
#define DH     64
#define SEG    512
#define PMEMN  16
#define TOK    8192        // 2*4096 tokens = 16 segments * 512
#define NQKV   3072
#define JPAD   544         // PMEM + SEG + 16 zero-pad (17 tiles of 32)
#define NSH    256         // 16 segments * 16 heads

typedef __hip_bfloat16 bf16;
typedef __attribute__((ext_vector_type(8))) short short8;   // 8 bf16 = 4 VGPRs
typedef __attribute__((ext_vector_type(4))) float floatx4;  // MFMA C/D frag

__device__ __forceinline__ short8 ld_frag(const bf16* p) {
    return *(const short8*)p;
}
__device__ __forceinline__ floatx4 mfma16(short8 a, short8 b, floatx4 c) {
    return __builtin_amdgcn_mfma_f32_16x16x32_bf16(a, b, c, 0, 0, 0);
}
__device__ __forceinline__ void st_out(bf16* p, float v) { *p = __float2bfloat16(v); }
__device__ __forceinline__ void st_out(float* p, float v) { *p = v; }

// ---------------- RMSNorm: fp32 in -> bf16 normalized ----------------
__global__ void rmsnorm_kernel(const float* __restrict__ x, const float* __restrict__ wgt,
                               bf16* __restrict__ xn) {
    int row = blockIdx.x;
    int tid = threadIdx.x;              // 256 threads, 4 floats each
    const float4* xr = (const float4*)(x + (long)row * DIM);
    float4 v = xr[tid];
    float ss = v.x * v.x + v.y * v.y + v.z * v.z + v.w * v.w;
    #pragma unroll
    for (int off = 32; off; off >>= 1) ss += __shfl_xor(ss, off);
    __shared__ float red[4];
    if ((tid & 63) == 0) red[tid >> 6] = ss;
    __syncthreads();
    float tot = red[0] + red[1] + red[2] + red[3];
    float sc = rsqrtf(tot * (1.0f / DIM) + 1.1920929e-07f);
    const float4* wr = (const float4*)wgt;
    float4 w4 = wr[tid];
    bf16* o = xn + (long)row * DIM + tid * 4;
    o[0] = __float2bfloat16(v.x * sc * w4.x);
    o[1] = __float2bfloat16(v.y * sc * w4.y);
    o[2] = __float2bfloat16(v.z * sc * w4.z);
    o[3] = __float2bfloat16(v.w * sc * w4.w);
}

// ------------- transpose + cast: fp32 [R][C] -> bf16 [C][R] ----------
__global__ void transpose_cast(const float* __restrict__ in, bf16* __restrict__ out,
                               int R, int C) {
    __shared__ float tile[32][33];
    int c0 = blockIdx.x * 32, r0 = blockIdx.y * 32;
    int tx = threadIdx.x, ty = threadIdx.y;      // (32,8)
    #pragma unroll
    for (int i = 0; i < 4; i++)
        tile[ty + i * 8][tx] = in[(long)(r0 + ty + i * 8) * C + c0 + tx];
    __syncthreads();
    #pragma unroll
    for (int i = 0; i < 4; i++)
        out[(long)(c0 + ty + i * 8) * R + r0 + tx] = __float2bfloat16(tile[tx][ty + i * 8]);
}

// ---------------- GEMM: C[M][N] = A[M][K] * Bt[N][K]^T, bf16 in, OT out ----------------
template <typename OT>
__global__ __launch_bounds__(256)
void gemm_bt(const bf16* __restrict__ A, const bf16* __restrict__ Bt,
             OT* __restrict__ C, int M, int N, int K) {
    __shared__ __align__(16) bf16 As[128 * 32];
    __shared__ __align__(16) bf16 Bs[128 * 32];
    const int tid = threadIdx.x;
    const int wv = tid >> 6;
    const int lane = tid & 63;
    const int quad = lane >> 4, l15 = lane & 15;
    const int wm = (wv >> 1) * 64, wn = (wv & 1) * 64;
    const int bm = blockIdx.x, bn = blockIdx.y;

    const int srow = wv * 16 + (lane >> 2);
    const int skof = (lane & 3) * 8;

    const bf16* Ag = A + (long)(bm * 128) * K;
    const bf16* Bg = Bt + (long)(bn * 128) * K;

    floatx4 acc[4][4] = {};

    for (int k0 = 0; k0 < K; k0 += 32) {
        short8 a0 = ld_frag(Ag + (long)srow * K + k0 + skof);
        short8 a1 = ld_frag(Ag + (long)(64 + srow) * K + k0 + skof);
        short8 b0 = ld_frag(Bg + (long)srow * K + k0 + skof);
        short8 b1 = ld_frag(Bg + (long)(64 + srow) * K + k0 + skof);
        __syncthreads();
        *(short8*)&As[srow * 32 + skof] = a0;
        *(short8*)&As[(64 + srow) * 32 + skof] = a1;
        *(short8*)&Bs[srow * 32 + skof] = b0;
        *(short8*)&Bs[(64 + srow) * 32 + skof] = b1;
        __syncthreads();
        short8 af[4], bfr[4];
        #pragma unroll
        for (int i = 0; i < 4; i++) af[i] = ld_frag(&As[(wm + i * 16 + l15) * 32 + quad * 8]);
        #pragma unroll
        for (int j = 0; j < 4; j++) bfr[j] = ld_frag(&Bs[(wn + j * 16 + l15) * 32 + quad * 8]);
        #pragma unroll
        for (int i = 0; i < 4; i++)
            #pragma unroll
            for (int j = 0; j < 4; j++)
                acc[i][j] = mfma16(af[i], bfr[j], acc[i][j]);
    }
    #pragma unroll
    for (int i = 0; i < 4; i++)
        #pragma unroll
        for (int j = 0; j < 4; j++) {
            int row = bm * 128 + wm + i * 16 + quad * 4;
            int col = bn * 128 + wn + j * 16 + l15;
            #pragma unroll
            for (int r = 0; r < 4; r++)
                st_out(&C[(long)(row + r) * N + col], acc[i][j][r]);
        }
}

// ------------- pmem rows into kpad/vtpad + zero tail pad -------------
__global__ void fill_pmem_pad(const float* __restrict__ pmem, bf16* __restrict__ kpad,
                              bf16* __restrict__ vtpad) {
    int gid = blockIdx.x * 256 + threadIdx.x;
    int dh = gid & 63, j = (gid >> 6) & 15, sh = gid >> 10;
    int h = sh & 15;
    float kv = pmem[((0 * HEADS + h) * PMEMN + j) * DH + dh];
    float vv = pmem[((1 * HEADS + h) * PMEMN + j) * DH + dh];
    kpad[((long)sh * JPAD + j) * DH + dh] = __float2bfloat16(kv);
    vtpad[((long)sh * DH + dh) * JPAD + j] = __float2bfloat16(vv);
    kpad[((long)sh * JPAD + PMEMN + SEG + j) * DH + dh] = __float2bfloat16(0.0f);
    vtpad[((long)sh * DH + dh) * JPAD + PMEMN + SEG + j] = __float2bfloat16(0.0f);
}

// ------------- RoPE: q in place in qkv; k -> kpad[sh][16+s][dh] -------------
__global__ void rope_qk(bf16* __restrict__ qkv, bf16* __restrict__ kpad) {
    int pid = blockIdx.x * 256 + threadIdx.x;
    int pr = pid & 31;
    int h  = (pid >> 5) & 15;
    int t  = (pid >> 9) & 8191;
    int qk = pid >> 22;
    int s  = t & 511;
    float invf = __expf(-(float)pr * (9.210340371976184f / 32.0f));
    float ang = (float)s * invf;
    float sn, cs;
    __sincosf(ang, &sn, &cs);
    long base = (long)t * NQKV + qk * DIM + h * DH + 2 * pr;
    float x1 = __bfloat162float(qkv[base]);
    float x2 = __bfloat162float(qkv[base + 1]);
    float y1 = x1 * cs - x2 * sn;
    float y2 = x2 * cs + x1 * sn;
    if (qk == 0) {
        qkv[base]     = __float2bfloat16(y1);
        qkv[base + 1] = __float2bfloat16(y2);
    } else {
        int sh = (t >> 9) * HEADS + h;
        long kb = ((long)sh * JPAD + PMEMN + s) * DH + 2 * pr;
        kpad[kb]     = __float2bfloat16(y1);
        kpad[kb + 1] = __float2bfloat16(y2);
    }
}

// ------- v: write orig_v output fp32 (sh,s,dh) + transposed vtpad[sh][dh][16+s] -------
__global__ void v_copy(const bf16* __restrict__ qkv, float* __restrict__ origv,
                       bf16* __restrict__ vtpad) {
    int sh = blockIdx.y;
    int s0 = blockIdx.x * 64;
    int bw = sh >> 4, h = sh & 15;
    __shared__ bf16 tile[64][65];
    #pragma unroll
    for (int i = 0; i < 16; i++) {
        int idx = i * 256 + threadIdx.x;
        int sr = idx >> 6, dh = idx & 63;
        bf16 v = qkv[(long)(bw * SEG + s0 + sr) * NQKV + 2 * DIM + h * DH + dh];
        tile[sr][dh] = v;
        origv[((long)sh * SEG + s0 + sr) * DH + dh] = __bfloat162float(v);
    }
    __syncthreads();
    #pragma unroll
    for (int i = 0; i < 16; i++) {
        int idx = i * 256 + threadIdx.x;
        int dh = idx >> 6, sr = idx & 63;
        vtpad[((long)sh * DH + dh) * JPAD + PMEMN + s0 + sr] = tile[sr][dh];
    }
}

// ------------- attention v2: 2-pass, uniform trip count, VALU PV -------------
__global__ __launch_bounds__(256)
void attn2(const bf16* __restrict__ qkv, const bf16* __restrict__ kpad,
           const bf16* __restrict__ vtpad, bf16* __restrict__ attn_out) {
    const int sh = blockIdx.y;
    const int wv = threadIdx.x >> 6;
    const int lane = threadIdx.x & 63;
    const int quad = lane >> 4, l15 = lane & 15;
    const int qr0 = blockIdx.x * 64 + wv * 16;
    const int bw = sh >> 4, h = sh & 15;
    const int NT = 2 * blockIdx.x + 3;   // uniform tiles/block

    __shared__ float pbuf[4][16 * 32];   // per-wave P-hat tile (fp32)
    float* pb = pbuf[wv];

    const bf16* qrow = qkv + (long)(bw * SEG + qr0 + l15) * NQKV + h * DH;
    short8 aq0 = ld_frag(qrow + quad * 8);
    short8 aq1 = ld_frag(qrow + 32 + quad * 8);

    const bf16* kb = kpad + (long)sh * JPAD * DH;
    const bf16* vb = vtpad + (long)sh * DH * JPAD;

    float mrow[4], lrow[4];
    #pragma unroll
    for (int r = 0; r < 4; r++) { mrow[r] = -1e30f; lrow[r] = 0.0f; }

    // ---- pass A: m and l ----
    for (int jt = 0; jt < NT; ++jt) {
        const int j0 = jt * 32;
        floatx4 s0 = {}, s1 = {};
        const bf16* kr0 = kb + (long)(j0 + l15) * DH;
        const bf16* kr1 = kb + (long)(j0 + 16 + l15) * DH;
        s0 = mfma16(aq0, ld_frag(kr0 + quad * 8), s0);
        s0 = mfma16(aq1, ld_frag(kr0 + 32 + quad * 8), s0);
        s1 = mfma16(aq0, ld_frag(kr1 + quad * 8), s1);
        s1 = mfma16(aq1, ld_frag(kr1 + 32 + quad * 8), s1);
        #pragma unroll
        for (int r = 0; r < 4; r++) {
            int qi = qr0 + quad * 4 + r;
            int ja = j0 + l15;
            int jb = j0 + 16 + l15;
            float va  = ((ja < PMEMN) || (ja - PMEMN <= qi)) ? s0[r] * 0.125f : -1e30f;
            float vb2 = ((jb < PMEMN) || (jb - PMEMN <= qi)) ? s1[r] * 0.125f : -1e30f;
            float rm = fmaxf(va, vb2);
            #pragma unroll
            for (int off = 1; off < 16; off <<= 1) rm = fmaxf(rm, __shfl_xor(rm, off));
            float mn = fmaxf(mrow[r], rm);
            float rs = __expf(va - mn) + __expf(vb2 - mn);
            #pragma unroll
            for (int off = 1; off < 16; off <<= 1) rs += __shfl_xor(rs, off);
            lrow[r] = lrow[r] * __expf(mrow[r] - mn) + rs;
            mrow[r] = mn;
        }
    }
    float invl[4];
    #pragma unroll
    for (int r = 0; r < 4; r++) invl[r] = 1.0f / lrow[r];

    // ---- pass B: P-hat + VALU PV ----
    float o[4][4] = {};   // o[r][n]: row = qr0+quad*4+r, dh = n*16+l15
    for (int jt = 0; jt < NT; ++jt) {
        const int j0 = jt * 32;
        floatx4 s0 = {}, s1 = {};
        const bf16* kr0 = kb + (long)(j0 + l15) * DH;
        const bf16* kr1 = kb + (long)(j0 + 16 + l15) * DH;
        s0 = mfma16(aq0, ld_frag(kr0 + quad * 8), s0);
        s0 = mfma16(aq1, ld_frag(kr0 + 32 + quad * 8), s0);
        s1 = mfma16(aq0, ld_frag(kr1 + quad * 8), s1);
        s1 = mfma16(aq1, ld_frag(kr1 + 32 + quad * 8), s1);
        __syncthreads();
        #pragma unroll
        for (int r = 0; r < 4; r++) {
            int qi = qr0 + quad * 4 + r;
            int ja = j0 + l15;
            int jb = j0 + 16 + l15;
            float va  = ((ja < PMEMN) || (ja - PMEMN <= qi)) ? s0[r] * 0.125f : -1e30f;
            float vb2 = ((jb < PMEMN) || (jb - PMEMN <= qi)) ? s1[r] * 0.125f : -1e30f;
            pb[(quad * 4 + r) * 32 + l15]      = __expf(va  - mrow[r]) * invl[r];
            pb[(quad * 4 + r) * 32 + 16 + l15] = __expf(vb2 - mrow[r]) * invl[r];
        }
        __syncthreads();
        #pragma unroll
        for (int j = 0; j < 32; j++) {
            float pv[4];
            #pragma unroll
            for (int r = 0; r < 4; r++) pv[r] = pb[(quad * 4 + r) * 32 + j];
            #pragma unroll
            for (int n = 0; n < 4; n++) {
                float vvv = __bfloat162float(vb[(long)(n * 16 + l15) * JPAD + j0 + j]);
                #pragma unroll
                for (int r = 0; r < 4; r++) o[r][n] += pv[r] * vvv;
            }
        }
    }
    bf16* orow = attn_out + (long)(bw * SEG + qr0 + quad * 4) * DIM + h * DH;
    #pragma unroll
    for (int r = 0; r < 4; r++)
        #pragma unroll
        for (int n = 0; n < 4; n++)
            orow[(long)r * DIM + n * 16 + l15] = __float2bfloat16(o[r][n]);
}

extern "C" void kernel_launch(void* const* d_in, const int* in_sizes, int n_in,
                              void* d_out, int out_size, void* d_ws, size_t ws_size,
                              hipStream_t stream) {
    const float* seq    = (const float*)d_in[0];
    const float* norm_w = (const float*)d_in[1];
    const float* w_qkv  = (const float*)d_in[2];
    const float* w_out  = (const float*)d_in[3];
    const float* pmem   = (const float*)d_in[4];
    // Reference outputs are FLOAT32 (jax fp32 pipeline): d_out = [out, orig_v] fp32.
    float* out   = (float*)d_out;
    float* origv = out + (long)TOK * DIM;

    char* p = (char*)d_ws;
    bf16* xn     = (bf16*)p; p += (long)TOK * DIM * 2;
    bf16* wqkvT  = (bf16*)p; p += (long)NQKV * DIM * 2;
    bf16* woutT  = (bf16*)p; p += (long)DIM * DIM * 2;
    bf16* qkv    = (bf16*)p; p += (long)TOK * NQKV * 2;
    bf16* kpadb  = (bf16*)p; p += (long)NSH * JPAD * DH * 2;
    bf16* vtpadb = (bf16*)p; p += (long)NSH * DH * JPAD * 2;
    bf16* attno  = xn;   // xn dead after QKV GEMM

    rmsnorm_kernel<<<TOK, 256, 0, stream>>>(seq, norm_w, xn);
    transpose_cast<<<dim3(NQKV / 32, DIM / 32), dim3(32, 8), 0, stream>>>(w_qkv, wqkvT, DIM, NQKV);
    transpose_cast<<<dim3(DIM / 32, DIM / 32), dim3(32, 8), 0, stream>>>(w_out, woutT, DIM, DIM);
    gemm_bt<bf16><<<dim3(TOK / 128, NQKV / 128), 256, 0, stream>>>(xn, wqkvT, qkv, TOK, NQKV, DIM);
    fill_pmem_pad<<<(NSH * PMEMN * DH) / 256, 256, 0, stream>>>(pmem, kpadb, vtpadb);
    rope_qk<<<(2L * TOK * HEADS * 32) / 256, 256, 0, stream>>>(qkv, kpadb);
    v_copy<<<dim3(SEG / 64, NSH), 256, 0, stream>>>(qkv, origv, vtpadb);
    attn2<<<dim3(SEG / 64, NSH), 256, 0, stream>>>(qkv, kpadb, vtpadb, attno);
    gemm_bt<float><<<dim3(TOK / 128, DIM / 128), 256, 0, stream>>>(attno, woutT, out, TOK, DIM, DIM);
}

// Round 5
// 333.936 us; speedup vs baseline: 5.7220x; 5.7220x over previous
//
#include <hip/hip_runtime.h>
#include <hip/hip_bf16.h>

#define DIM    1024
#define HEADS  16
#define DH     64
#define SEG    512
#define PMEMN  16
#define TOK    8192        // 2*4096 tokens = 16 segments * 512
#define NQKV   3072
#define JPAD   544         // PMEM + SEG + 16 zero-pad (17 tiles of 32)
#define NSH    256         // 16 segments * 16 heads

typedef __hip_bfloat16 bf16;
typedef __attribute__((ext_vector_type(8))) short short8;   // 8 bf16 = 4 VGPRs
typedef __attribute__((ext_vector_type(4))) float floatx4;  // MFMA C/D frag

__device__ __forceinline__ short8 ld_frag(const bf16* p) {
    return *(const short8*)p;
}
__device__ __forceinline__ floatx4 mfma16(short8 a, short8 b, floatx4 c) {
    return __builtin_amdgcn_mfma_f32_16x16x32_bf16(a, b, c, 0, 0, 0);
}
__device__ __forceinline__ void st_out(bf16* p, float v) { *p = __float2bfloat16(v); }
__device__ __forceinline__ void st_out(float* p, float v) { *p = v; }

// ---------------- RMSNorm: fp32 in -> bf16 normalized ----------------
__global__ void rmsnorm_kernel(const float* __restrict__ x, const float* __restrict__ wgt,
                               bf16* __restrict__ xn) {
    int row = blockIdx.x;
    int tid = threadIdx.x;              // 256 threads, 4 floats each
    const float4* xr = (const float4*)(x + (long)row * DIM);
    float4 v = xr[tid];
    float ss = v.x * v.x + v.y * v.y + v.z * v.z + v.w * v.w;
    #pragma unroll
    for (int off = 32; off; off >>= 1) ss += __shfl_xor(ss, off);
    __shared__ float red[4];
    if ((tid & 63) == 0) red[tid >> 6] = ss;
    __syncthreads();
    float tot = red[0] + red[1] + red[2] + red[3];
    float sc = rsqrtf(tot * (1.0f / DIM) + 1.1920929e-07f);
    const float4* wr = (const float4*)wgt;
    float4 w4 = wr[tid];
    bf16* o = xn + (long)row * DIM + tid * 4;
    o[0] = __float2bfloat16(v.x * sc * w4.x);
    o[1] = __float2bfloat16(v.y * sc * w4.y);
    o[2] = __float2bfloat16(v.z * sc * w4.z);
    o[3] = __float2bfloat16(v.w * sc * w4.w);
}

// ------------- transpose + cast: fp32 [R][C] -> bf16 [C][R] ----------
__global__ void transpose_cast(const float* __restrict__ in, bf16* __restrict__ out,
                               int R, int C) {
    __shared__ float tile[32][33];
    int c0 = blockIdx.x * 32, r0 = blockIdx.y * 32;
    int tx = threadIdx.x, ty = threadIdx.y;      // (32,8)
    #pragma unroll
    for (int i = 0; i < 4; i++)
        tile[ty + i * 8][tx] = in[(long)(r0 + ty + i * 8) * C + c0 + tx];
    __syncthreads();
    #pragma unroll
    for (int i = 0; i < 4; i++)
        out[(long)(c0 + ty + i * 8) * R + r0 + tx] = __float2bfloat16(tile[tx][ty + i * 8]);
}

// ---------------- GEMM: C[M][N] = A[M][K] * Bt[N][K]^T, bf16 in, OT out ----------------
template <typename OT>
__global__ __launch_bounds__(256)
void gemm_bt(const bf16* __restrict__ A, const bf16* __restrict__ Bt,
             OT* __restrict__ C, int M, int N, int K) {
    __shared__ __align__(16) bf16 As[128 * 32];
    __shared__ __align__(16) bf16 Bs[128 * 32];
    const int tid = threadIdx.x;
    const int wv = tid >> 6;
    const int lane = tid & 63;
    const int quad = lane >> 4, l15 = lane & 15;
    const int wm = (wv >> 1) * 64, wn = (wv & 1) * 64;
    const int bm = blockIdx.x, bn = blockIdx.y;

    const int srow = wv * 16 + (lane >> 2);
    const int skof = (lane & 3) * 8;

    const bf16* Ag = A + (long)(bm * 128) * K;
    const bf16* Bg = Bt + (long)(bn * 128) * K;

    floatx4 acc[4][4] = {};

    for (int k0 = 0; k0 < K; k0 += 32) {
        short8 a0 = ld_frag(Ag + (long)srow * K + k0 + skof);
        short8 a1 = ld_frag(Ag + (long)(64 + srow) * K + k0 + skof);
        short8 b0 = ld_frag(Bg + (long)srow * K + k0 + skof);
        short8 b1 = ld_frag(Bg + (long)(64 + srow) * K + k0 + skof);
        __syncthreads();
        *(short8*)&As[srow * 32 + skof] = a0;
        *(short8*)&As[(64 + srow) * 32 + skof] = a1;
        *(short8*)&Bs[srow * 32 + skof] = b0;
        *(short8*)&Bs[(64 + srow) * 32 + skof] = b1;
        __syncthreads();
        short8 af[4], bfr[4];
        #pragma unroll
        for (int i = 0; i < 4; i++) af[i] = ld_frag(&As[(wm + i * 16 + l15) * 32 + quad * 8]);
        #pragma unroll
        for (int j = 0; j < 4; j++) bfr[j] = ld_frag(&Bs[(wn + j * 16 + l15) * 32 + quad * 8]);
        #pragma unroll
        for (int i = 0; i < 4; i++)
            #pragma unroll
            for (int j = 0; j < 4; j++)
                acc[i][j] = mfma16(af[i], bfr[j], acc[i][j]);
    }
    #pragma unroll
    for (int i = 0; i < 4; i++)
        #pragma unroll
        for (int j = 0; j < 4; j++) {
            int row = bm * 128 + wm + i * 16 + quad * 4;
            int col = bn * 128 + wn + j * 16 + l15;
            #pragma unroll
            for (int r = 0; r < 4; r++)
                st_out(&C[(long)(row + r) * N + col], acc[i][j][r]);
        }
}

// ------------- pmem rows into kpad/vtpad + zero tail pad -------------
__global__ void fill_pmem_pad(const float* __restrict__ pmem, bf16* __restrict__ kpad,
                              bf16* __restrict__ vtpad) {
    int gid = blockIdx.x * 256 + threadIdx.x;
    int dh = gid & 63, j = (gid >> 6) & 15, sh = gid >> 10;
    int h = sh & 15;
    float kv = pmem[((0 * HEADS + h) * PMEMN + j) * DH + dh];
    float vv = pmem[((1 * HEADS + h) * PMEMN + j) * DH + dh];
    kpad[((long)sh * JPAD + j) * DH + dh] = __float2bfloat16(kv);
    vtpad[((long)sh * DH + dh) * JPAD + j] = __float2bfloat16(vv);
    kpad[((long)sh * JPAD + PMEMN + SEG + j) * DH + dh] = __float2bfloat16(0.0f);
    vtpad[((long)sh * DH + dh) * JPAD + PMEMN + SEG + j] = __float2bfloat16(0.0f);
}

// ------------- RoPE: q in place in qkv; k -> kpad[sh][16+s][dh] -------------
__global__ void rope_qk(bf16* __restrict__ qkv, bf16* __restrict__ kpad) {
    int pid = blockIdx.x * 256 + threadIdx.x;
    int pr = pid & 31;
    int h  = (pid >> 5) & 15;
    int t  = (pid >> 9) & 8191;
    int qk = pid >> 22;
    int s  = t & 511;
    float invf = __expf(-(float)pr * (9.210340371976184f / 32.0f));
    float ang = (float)s * invf;
    float sn, cs;
    __sincosf(ang, &sn, &cs);
    long base = (long)t * NQKV + qk * DIM + h * DH + 2 * pr;
    float x1 = __bfloat162float(qkv[base]);
    float x2 = __bfloat162float(qkv[base + 1]);
    float y1 = x1 * cs - x2 * sn;
    float y2 = x2 * cs + x1 * sn;
    if (qk == 0) {
        qkv[base]     = __float2bfloat16(y1);
        qkv[base + 1] = __float2bfloat16(y2);
    } else {
        int sh = (t >> 9) * HEADS + h;
        long kb = ((long)sh * JPAD + PMEMN + s) * DH + 2 * pr;
        kpad[kb]     = __float2bfloat16(y1);
        kpad[kb + 1] = __float2bfloat16(y2);
    }
}

// ------- v: write orig_v output fp32 (sh,s,dh) + transposed vtpad[sh][dh][16+s] -------
__global__ void v_copy(const bf16* __restrict__ qkv, float* __restrict__ origv,
                       bf16* __restrict__ vtpad) {
    int sh = blockIdx.y;
    int s0 = blockIdx.x * 64;
    int bw = sh >> 4, h = sh & 15;
    __shared__ bf16 tile[64][65];
    #pragma unroll
    for (int i = 0; i < 16; i++) {
        int idx = i * 256 + threadIdx.x;
        int sr = idx >> 6, dh = idx & 63;
        bf16 v = qkv[(long)(bw * SEG + s0 + sr) * NQKV + 2 * DIM + h * DH + dh];
        tile[sr][dh] = v;
        origv[((long)sh * SEG + s0 + sr) * DH + dh] = __bfloat162float(v);
    }
    __syncthreads();
    #pragma unroll
    for (int i = 0; i < 16; i++) {
        int idx = i * 256 + threadIdx.x;
        int dh = idx >> 6, sr = idx & 63;
        vtpad[((long)sh * DH + dh) * JPAD + PMEMN + s0 + sr] = tile[sr][dh];
    }
}

// ---------------- flash attention: 1 wave = 16 q rows, K/V tiles of 32, MFMA PV ----------------
__global__ __launch_bounds__(256)
void flash_attn(const bf16* __restrict__ qkv, const bf16* __restrict__ kpad,
                const bf16* __restrict__ vtpad, bf16* __restrict__ attn_out) {
    const int sh = blockIdx.y;
    const int wv = threadIdx.x >> 6;
    const int lane = threadIdx.x & 63;
    const int quad = lane >> 4, l15 = lane & 15;
    const int qr0 = blockIdx.x * 64 + wv * 16;
    const int bw = sh >> 4, h = sh & 15;

    // P round-trip buffer (C-layout -> A-fragment-layout). Wave-local; DS ops
    // are in-order within a wave; memcpy + asm barriers stop compiler reorder.
    __shared__ __align__(16) short pbuf[4][16 * 32];
    short* pb = pbuf[wv];

    const bf16* qrow = qkv + (long)(bw * SEG + qr0 + l15) * NQKV + h * DH;
    short8 aq0 = ld_frag(qrow + quad * 8);
    short8 aq1 = ld_frag(qrow + 32 + quad * 8);

    float mrow[4], lrow[4];
    floatx4 o[4] = {};
    #pragma unroll
    for (int r = 0; r < 4; r++) { mrow[r] = -1e30f; lrow[r] = 0.0f; }

    const bf16* kb = kpad + (long)sh * JPAD * DH;
    const bf16* vb = vtpad + (long)sh * DH * JPAD;

    const int ntiles = (qr0 + 31) / 32 + 1;   // causal: j0 <= qr0+31
    for (int jt = 0; jt < ntiles; ++jt) {
        const int j0 = jt * 32;
        floatx4 s0 = {}, s1 = {};
        {
            const bf16* kr0 = kb + (long)(j0 + l15) * DH;
            const bf16* kr1 = kb + (long)(j0 + 16 + l15) * DH;
            s0 = mfma16(aq0, ld_frag(kr0 + quad * 8), s0);
            s0 = mfma16(aq1, ld_frag(kr0 + 32 + quad * 8), s0);
            s1 = mfma16(aq0, ld_frag(kr1 + quad * 8), s1);
            s1 = mfma16(aq1, ld_frag(kr1 + 32 + quad * 8), s1);
        }
        float alpha[4];
        #pragma unroll
        for (int r = 0; r < 4; r++) {
            int qi = qr0 + quad * 4 + r;
            int ja = j0 + l15;
            int jb = j0 + 16 + l15;
            float va  = ((ja < PMEMN) || (ja - PMEMN <= qi)) ? s0[r] * 0.125f : -1e30f;
            float vb2 = ((jb < PMEMN) || (jb - PMEMN <= qi)) ? s1[r] * 0.125f : -1e30f;
            float rm = fmaxf(va, vb2);
            #pragma unroll
            for (int off = 1; off < 16; off <<= 1) rm = fmaxf(rm, __shfl_xor(rm, off));
            float mn = fmaxf(mrow[r], rm);
            alpha[r] = __expf(mrow[r] - mn);
            mrow[r] = mn;
            float p0 = __expf(va - mn);
            float p1 = __expf(vb2 - mn);
            float rs = p0 + p1;
            #pragma unroll
            for (int off = 1; off < 16; off <<= 1) rs += __shfl_xor(rs, off);
            lrow[r] = lrow[r] * alpha[r] + rs;
            pb[(quad * 4 + r) * 32 + l15]      = __builtin_bit_cast(short, __float2bfloat16(p0));
            pb[(quad * 4 + r) * 32 + 16 + l15] = __builtin_bit_cast(short, __float2bfloat16(p1));
        }
        __asm__ volatile("" ::: "memory");
        short8 pa;
        __builtin_memcpy(&pa, &pb[l15 * 32 + quad * 8], 16);
        __asm__ volatile("" ::: "memory");
        #pragma unroll
        for (int n = 0; n < 4; n++) {
            short8 bv = ld_frag(vb + (long)(n * 16 + l15) * JPAD + j0 + quad * 8);
            #pragma unroll
            for (int r = 0; r < 4; r++) o[n][r] *= alpha[r];
            o[n] = mfma16(pa, bv, o[n]);
        }
    }
    bf16* orow = attn_out + (long)(bw * SEG + qr0 + quad * 4) * DIM + h * DH;
    #pragma unroll
    for (int r = 0; r < 4; r++) {
        float inv = 1.0f / lrow[r];
        #pragma unroll
        for (int n = 0; n < 4; n++)
            orow[(long)r * DIM + n * 16 + l15] = __float2bfloat16(o[n][r] * inv);
    }
}

extern "C" void kernel_launch(void* const* d_in, const int* in_sizes, int n_in,
                              void* d_out, int out_size, void* d_ws, size_t ws_size,
                              hipStream_t stream) {
    const float* seq    = (const float*)d_in[0];
    const float* norm_w = (const float*)d_in[1];
    const float* w_qkv  = (const float*)d_in[2];
    const float* w_out  = (const float*)d_in[3];
    const float* pmem   = (const float*)d_in[4];
    // Reference outputs are FLOAT32: d_out = [out, orig_v] fp32.
    float* out   = (float*)d_out;
    float* origv = out + (long)TOK * DIM;

    char* p = (char*)d_ws;
    bf16* xn     = (bf16*)p; p += (long)TOK * DIM * 2;
    bf16* wqkvT  = (bf16*)p; p += (long)NQKV * DIM * 2;
    bf16* woutT  = (bf16*)p; p += (long)DIM * DIM * 2;
    bf16* qkv    = (bf16*)p; p += (long)TOK * NQKV * 2;
    bf16* kpadb  = (bf16*)p; p += (long)NSH * JPAD * DH * 2;
    bf16* vtpadb = (bf16*)p; p += (long)NSH * DH * JPAD * 2;
    bf16* attno  = xn;   // xn dead after QKV GEMM

    rmsnorm_kernel<<<TOK, 256, 0, stream>>>(seq, norm_w, xn);
    transpose_cast<<<dim3(NQKV / 32, DIM / 32), dim3(32, 8), 0, stream>>>(w_qkv, wqkvT, DIM, NQKV);
    transpose_cast<<<dim3(DIM / 32, DIM / 32), dim3(32, 8), 0, stream>>>(w_out, woutT, DIM, DIM);
    gemm_bt<bf16><<<dim3(TOK / 128, NQKV / 128), 256, 0, stream>>>(xn, wqkvT, qkv, TOK, NQKV, DIM);
    fill_pmem_pad<<<(NSH * PMEMN * DH) / 256, 256, 0, stream>>>(pmem, kpadb, vtpadb);
    rope_qk<<<(2L * TOK * HEADS * 32) / 256, 256, 0, stream>>>(qkv, kpadb);
    v_copy<<<dim3(SEG / 64, NSH), 256, 0, stream>>>(qkv, origv, vtpadb);
    flash_attn<<<dim3(SEG / 64, NSH), 256, 0, stream>>>(qkv, kpadb, vtpadb, attno);
    gemm_bt<float><<<dim3(TOK / 128, DIM / 128), 256, 0, stream>>>(attno, woutT, out, TOK, DIM, DIM);
}

// Round 6
// 286.684 us; speedup vs baseline: 6.6651x; 1.1648x over previous
//
#include <hip/hip_runtime.h>
#include <hip/hip_bf16.h>

#define DIM    1024
#define HEADS  16
#define DH     64
#define SEG    512
#define PMEMN  16
#define TOK    8192        // 2*4096 tokens = 16 segments * 512
#define NQKV   3072
#define JPAD   544         // PMEM + SEG + 16 zero-pad (17 tiles of 32)
#define NSH    256         // 16 segments * 16 heads

typedef __hip_bfloat16 bf16;
typedef __attribute__((ext_vector_type(8))) short short8;   // 8 bf16 = 4 VGPRs
typedef __attribute__((ext_vector_type(4))) float floatx4;  // MFMA C/D frag

__device__ __forceinline__ short8 ld_frag(const bf16* p) {
    return *(const short8*)p;
}
__device__ __forceinline__ floatx4 mfma16(short8 a, short8 b, floatx4 c) {
    return __builtin_amdgcn_mfma_f32_16x16x32_bf16(a, b, c, 0, 0, 0);
}
__device__ __forceinline__ void st_out(bf16* p, float v) { *p = __float2bfloat16(v); }
__device__ __forceinline__ void st_out(float* p, float v) { *p = v; }
// async global->LDS DMA, 16 B per lane; LDS dest = wave base + lane*16
__device__ __forceinline__ void g2lds16(const bf16* g, bf16* l) {
    __builtin_amdgcn_global_load_lds((const __attribute__((address_space(1))) void*)g,
                                     (__attribute__((address_space(3))) void*)l, 16, 0, 0);
}

// ---------------- RMSNorm: fp32 in -> bf16 normalized ----------------
__global__ void rmsnorm_kernel(const float* __restrict__ x, const float* __restrict__ wgt,
                               bf16* __restrict__ xn) {
    int row = blockIdx.x;
    int tid = threadIdx.x;              // 256 threads, 4 floats each
    const float4* xr = (const float4*)(x + (long)row * DIM);
    float4 v = xr[tid];
    float ss = v.x * v.x + v.y * v.y + v.z * v.z + v.w * v.w;
    #pragma unroll
    for (int off = 32; off; off >>= 1) ss += __shfl_xor(ss, off);
    __shared__ float red[4];
    if ((tid & 63) == 0) red[tid >> 6] = ss;
    __syncthreads();
    float tot = red[0] + red[1] + red[2] + red[3];
    float sc = rsqrtf(tot * (1.0f / DIM) + 1.1920929e-07f);
    const float4* wr = (const float4*)wgt;
    float4 w4 = wr[tid];
    bf16* o = xn + (long)row * DIM + tid * 4;
    o[0] = __float2bfloat16(v.x * sc * w4.x);
    o[1] = __float2bfloat16(v.y * sc * w4.y);
    o[2] = __float2bfloat16(v.z * sc * w4.z);
    o[3] = __float2bfloat16(v.w * sc * w4.w);
}

// ------------- transpose + cast: fp32 [R][C] -> bf16 [C][R] ----------
__global__ void transpose_cast(const float* __restrict__ in, bf16* __restrict__ out,
                               int R, int C) {
    __shared__ float tile[32][33];
    int c0 = blockIdx.x * 32, r0 = blockIdx.y * 32;
    int tx = threadIdx.x, ty = threadIdx.y;      // (32,8)
    #pragma unroll
    for (int i = 0; i < 4; i++)
        tile[ty + i * 8][tx] = in[(long)(r0 + ty + i * 8) * C + c0 + tx];
    __syncthreads();
    #pragma unroll
    for (int i = 0; i < 4; i++)
        out[(long)(c0 + ty + i * 8) * R + r0 + tx] = __float2bfloat16(tile[tx][ty + i * 8]);
}

// ------- GEMM: C[M][N] = A[M][K] * Bt[N][K]^T, bf16 in, OT out, async LDS staging -------
template <typename OT>
__global__ __launch_bounds__(256)
void gemm_bt(const bf16* __restrict__ A, const bf16* __restrict__ Bt,
             OT* __restrict__ C, int M, int N, int K) {
    __shared__ __align__(16) bf16 As[128 * 32];
    __shared__ __align__(16) bf16 Bs[128 * 32];
    const int tid = threadIdx.x;
    const int wv = tid >> 6;
    const int lane = tid & 63;
    const int quad = lane >> 4, l15 = lane & 15;
    const int wm = (wv >> 1) * 64, wn = (wv & 1) * 64;
    const int bm = blockIdx.x, bn = blockIdx.y;

    const int srow = tid >> 2;          // 0..63: row within 64-row half
    const int skof = (tid & 3) * 8;     // 8 bf16 = 16 B within row

    const bf16* Ag = A + (long)(bm * 128 + srow) * K + skof;
    const bf16* Bg = Bt + (long)(bn * 128 + srow) * K + skof;
    const long half = (long)64 * K;

    floatx4 acc[4][4] = {};

    for (int k0 = 0; k0 < K; k0 += 32) {
        __syncthreads();                 // prior iter's ds_reads done before DMA overwrite
        g2lds16(Ag + k0,        As + tid * 8);          // rows 0..63
        g2lds16(Ag + half + k0, As + 2048 + tid * 8);   // rows 64..127
        g2lds16(Bg + k0,        Bs + tid * 8);
        g2lds16(Bg + half + k0, Bs + 2048 + tid * 8);
        __syncthreads();                 // drains vmcnt(0): DMA landed
        short8 af[4], bfr[4];
        #pragma unroll
        for (int i = 0; i < 4; i++) af[i] = ld_frag(&As[(wm + i * 16 + l15) * 32 + quad * 8]);
        #pragma unroll
        for (int j = 0; j < 4; j++) bfr[j] = ld_frag(&Bs[(wn + j * 16 + l15) * 32 + quad * 8]);
        #pragma unroll
        for (int i = 0; i < 4; i++)
            #pragma unroll
            for (int j = 0; j < 4; j++)
                acc[i][j] = mfma16(af[i], bfr[j], acc[i][j]);
    }
    #pragma unroll
    for (int i = 0; i < 4; i++)
        #pragma unroll
        for (int j = 0; j < 4; j++) {
            int row = bm * 128 + wm + i * 16 + quad * 4;
            int col = bn * 128 + wn + j * 16 + l15;
            #pragma unroll
            for (int r = 0; r < 4; r++)
                st_out(&C[(long)(row + r) * N + col], acc[i][j][r]);
        }
}

// ------------- pmem rows into kpad/vtpad + zero tail pad -------------
__global__ void fill_pmem_pad(const float* __restrict__ pmem, bf16* __restrict__ kpad,
                              bf16* __restrict__ vtpad) {
    int gid = blockIdx.x * 256 + threadIdx.x;
    int dh = gid & 63, j = (gid >> 6) & 15, sh = gid >> 10;
    int h = sh & 15;
    float kv = pmem[((0 * HEADS + h) * PMEMN + j) * DH + dh];
    float vv = pmem[((1 * HEADS + h) * PMEMN + j) * DH + dh];
    kpad[((long)sh * JPAD + j) * DH + dh] = __float2bfloat16(kv);
    vtpad[((long)sh * DH + dh) * JPAD + j] = __float2bfloat16(vv);
    kpad[((long)sh * JPAD + PMEMN + SEG + j) * DH + dh] = __float2bfloat16(0.0f);
    vtpad[((long)sh * DH + dh) * JPAD + PMEMN + SEG + j] = __float2bfloat16(0.0f);
}

// --- RoPE: q in place in qkv (pre-scaled by 2^-3, bf16-exact); k -> kpad ---
__global__ void rope_qk(bf16* __restrict__ qkv, bf16* __restrict__ kpad) {
    int pid = blockIdx.x * 256 + threadIdx.x;
    int pr = pid & 31;
    int h  = (pid >> 5) & 15;
    int t  = (pid >> 9) & 8191;
    int qk = pid >> 22;
    int s  = t & 511;
    float invf = __expf(-(float)pr * (9.210340371976184f / 32.0f));
    float ang = (float)s * invf;
    float sn, cs;
    __sincosf(ang, &sn, &cs);
    long base = (long)t * NQKV + qk * DIM + h * DH + 2 * pr;
    float x1 = __bfloat162float(qkv[base]);
    float x2 = __bfloat162float(qkv[base + 1]);
    float y1 = x1 * cs - x2 * sn;
    float y2 = x2 * cs + x1 * sn;
    if (qk == 0) {
        qkv[base]     = __float2bfloat16(y1 * 0.125f);   // fold DH^-0.5 into q (exact)
        qkv[base + 1] = __float2bfloat16(y2 * 0.125f);
    } else {
        int sh = (t >> 9) * HEADS + h;
        long kb = ((long)sh * JPAD + PMEMN + s) * DH + 2 * pr;
        kpad[kb]     = __float2bfloat16(y1);
        kpad[kb + 1] = __float2bfloat16(y2);
    }
}

// ------- v: write orig_v output fp32 (sh,s,dh) + transposed vtpad[sh][dh][16+s] -------
__global__ void v_copy(const bf16* __restrict__ qkv, float* __restrict__ origv,
                       bf16* __restrict__ vtpad) {
    int sh = blockIdx.y;
    int s0 = blockIdx.x * 64;
    int bw = sh >> 4, h = sh & 15;
    __shared__ bf16 tile[64][65];
    #pragma unroll
    for (int i = 0; i < 16; i++) {
        int idx = i * 256 + threadIdx.x;
        int sr = idx >> 6, dh = idx & 63;
        bf16 v = qkv[(long)(bw * SEG + s0 + sr) * NQKV + 2 * DIM + h * DH + dh];
        tile[sr][dh] = v;
        origv[((long)sh * SEG + s0 + sr) * DH + dh] = __bfloat162float(v);
    }
    __syncthreads();
    #pragma unroll
    for (int i = 0; i < 16; i++) {
        int idx = i * 256 + threadIdx.x;
        int dh = idx >> 6, sr = idx & 63;
        vtpad[((long)sh * DH + dh) * JPAD + PMEMN + s0 + sr] = tile[sr][dh];
    }
}

// ------- flash attention: 1 wave = 32 q rows (2 groups share K/V loads), MFMA PV -------
// grid: 1024 blocks, id = qblk*NSH + sh  (same-sh blocks land on same XCD: id%8 = sh%8)
__global__ __launch_bounds__(256, 3)
void flash_attn(const bf16* __restrict__ qkv, const bf16* __restrict__ kpad,
                const bf16* __restrict__ vtpad, bf16* __restrict__ attn_out) {
    const int bid = blockIdx.x;
    const int sh = bid & (NSH - 1);
    const int qblk = bid >> 8;
    const int wv = threadIdx.x >> 6;
    const int lane = threadIdx.x & 63;
    const int quad = lane >> 4, l15 = lane & 15;
    const int qr0 = qblk * 128 + wv * 32;
    const int bw = sh >> 4, h = sh & 15;

    // per-wave 32x32 P tile (two 16-row groups), short-typed + memcpy read (TBAA-safe)
    __shared__ __align__(16) short pbuf[4][32 * 32];
    short* pb = pbuf[wv];

    const bf16* qr_g0 = qkv + (long)(bw * SEG + qr0 + l15) * NQKV + h * DH;
    const bf16* qr_g1 = qkv + (long)(bw * SEG + qr0 + 16 + l15) * NQKV + h * DH;
    short8 aq[2][2] = {{ld_frag(qr_g0 + quad * 8), ld_frag(qr_g0 + 32 + quad * 8)},
                       {ld_frag(qr_g1 + quad * 8), ld_frag(qr_g1 + 32 + quad * 8)}};

    float mrow[2][4], lrow[2][4];
    floatx4 o[2][4] = {};
    #pragma unroll
    for (int g = 0; g < 2; g++)
        #pragma unroll
        for (int r = 0; r < 4; r++) { mrow[g][r] = -1e30f; lrow[g][r] = 0.0f; }

    const bf16* kb = kpad + (long)sh * JPAD * DH;
    const bf16* vbp = vtpad + (long)sh * DH * JPAD;

    const int ntiles = (qr0 + 47) / 32 + 1;   // causal: j0 <= qr0+31+16
    for (int jt = 0; jt < ntiles; ++jt) {
        const int j0 = jt * 32;
        // shared K fragments (j rows j0..j0+31, two 16-col B-frags x two k-halves)
        const bf16* kr0 = kb + (long)(j0 + l15) * DH;
        const bf16* kr1 = kb + (long)(j0 + 16 + l15) * DH;
        short8 k00 = ld_frag(kr0 + quad * 8);
        short8 k01 = ld_frag(kr0 + 32 + quad * 8);
        short8 k10 = ld_frag(kr1 + quad * 8);
        short8 k11 = ld_frag(kr1 + 32 + quad * 8);
        // shared V fragments
        short8 bv[4];
        #pragma unroll
        for (int n = 0; n < 4; n++)
            bv[n] = ld_frag(vbp + (long)(n * 16 + l15) * JPAD + j0 + quad * 8);

        float alpha[2][4];
        #pragma unroll
        for (int g = 0; g < 2; g++) {
            floatx4 s0 = {}, s1 = {};
            s0 = mfma16(aq[g][0], k00, s0);
            s0 = mfma16(aq[g][1], k01, s0);
            s1 = mfma16(aq[g][0], k10, s1);
            s1 = mfma16(aq[g][1], k11, s1);
            #pragma unroll
            for (int r = 0; r < 4; r++) {
                int qi = qr0 + g * 16 + quad * 4 + r;
                int ja = j0 + l15;
                int jb = j0 + 16 + l15;
                float va  = ((ja < PMEMN) || (ja - PMEMN <= qi)) ? s0[r] : -1e30f;
                float vb2 = ((jb < PMEMN) || (jb - PMEMN <= qi)) ? s1[r] : -1e30f;
                float rm = fmaxf(va, vb2);
                #pragma unroll
                for (int off = 1; off < 16; off <<= 1) rm = fmaxf(rm, __shfl_xor(rm, off));
                float mn = fmaxf(mrow[g][r], rm);
                alpha[g][r] = __expf(mrow[g][r] - mn);
                mrow[g][r] = mn;
                float p0 = __expf(va - mn);
                float p1 = __expf(vb2 - mn);
                float rs = p0 + p1;
                #pragma unroll
                for (int off = 1; off < 16; off <<= 1) rs += __shfl_xor(rs, off);
                lrow[g][r] = lrow[g][r] * alpha[g][r] + rs;
                pb[(g * 16 + quad * 4 + r) * 32 + l15]      = __builtin_bit_cast(short, __float2bfloat16(p0));
                pb[(g * 16 + quad * 4 + r) * 32 + 16 + l15] = __builtin_bit_cast(short, __float2bfloat16(p1));
            }
        }
        __asm__ volatile("" ::: "memory");
        short8 pa0, pa1;
        __builtin_memcpy(&pa0, &pb[l15 * 32 + quad * 8], 16);
        __builtin_memcpy(&pa1, &pb[(16 + l15) * 32 + quad * 8], 16);
        __asm__ volatile("" ::: "memory");
        #pragma unroll
        for (int n = 0; n < 4; n++) {
            #pragma unroll
            for (int r = 0; r < 4; r++) { o[0][n][r] *= alpha[0][r]; o[1][n][r] *= alpha[1][r]; }
            o[0][n] = mfma16(pa0, bv[n], o[0][n]);
            o[1][n] = mfma16(pa1, bv[n], o[1][n]);
        }
    }
    #pragma unroll
    for (int g = 0; g < 2; g++) {
        bf16* orow = attn_out + (long)(bw * SEG + qr0 + g * 16 + quad * 4) * DIM + h * DH;
        #pragma unroll
        for (int r = 0; r < 4; r++) {
            float inv = 1.0f / lrow[g][r];
            #pragma unroll
            for (int n = 0; n < 4; n++)
                orow[(long)r * DIM + n * 16 + l15] = __float2bfloat16(o[g][n][r] * inv);
        }
    }
}

extern "C" void kernel_launch(void* const* d_in, const int* in_sizes, int n_in,
                              void* d_out, int out_size, void* d_ws, size_t ws_size,
                              hipStream_t stream) {
    const float* seq    = (const float*)d_in[0];
    const float* norm_w = (const float*)d_in[1];
    const float* w_qkv  = (const float*)d_in[2];
    const float* w_out  = (const float*)d_in[3];
    const float* pmem   = (const float*)d_in[4];
    // Reference outputs are FLOAT32: d_out = [out, orig_v] fp32.
    float* out   = (float*)d_out;
    float* origv = out + (long)TOK * DIM;

    char* p = (char*)d_ws;
    bf16* xn     = (bf16*)p; p += (long)TOK * DIM * 2;
    bf16* wqkvT  = (bf16*)p; p += (long)NQKV * DIM * 2;
    bf16* woutT  = (bf16*)p; p += (long)DIM * DIM * 2;
    bf16* qkv    = (bf16*)p; p += (long)TOK * NQKV * 2;
    bf16* kpadb  = (bf16*)p; p += (long)NSH * JPAD * DH * 2;
    bf16* vtpadb = (bf16*)p; p += (long)NSH * DH * JPAD * 2;
    bf16* attno  = xn;   // xn dead after QKV GEMM

    rmsnorm_kernel<<<TOK, 256, 0, stream>>>(seq, norm_w, xn);
    transpose_cast<<<dim3(NQKV / 32, DIM / 32), dim3(32, 8), 0, stream>>>(w_qkv, wqkvT, DIM, NQKV);
    transpose_cast<<<dim3(DIM / 32, DIM / 32), dim3(32, 8), 0, stream>>>(w_out, woutT, DIM, DIM);
    gemm_bt<bf16><<<dim3(TOK / 128, NQKV / 128), 256, 0, stream>>>(xn, wqkvT, qkv, TOK, NQKV, DIM);
    fill_pmem_pad<<<(NSH * PMEMN * DH) / 256, 256, 0, stream>>>(pmem, kpadb, vtpadb);
    rope_qk<<<(2L * TOK * HEADS * 32) / 256, 256, 0, stream>>>(qkv, kpadb);
    v_copy<<<dim3(SEG / 64, NSH), 256, 0, stream>>>(qkv, origv, vtpadb);
    flash_attn<<<4 * NSH, 256, 0, stream>>>(qkv, kpadb, vtpadb, attno);
    gemm_bt<float><<<dim3(TOK / 128, DIM / 128), 256, 0, stream>>>(attno, woutT, out, TOK, DIM, DIM);
}

// Round 7
// 281.648 us; speedup vs baseline: 6.7843x; 1.0179x over previous
//
#include <hip/hip_runtime.h>
#include <hip/hip_bf16.h>

#define DIM    1024
#define HEADS  16
#define DH     64
#define SEG    512
#define PMEMN  16
#define TOK    8192        // 2*4096 tokens = 16 segments * 512
#define NQKV   3072
#define JPAD   544         // PMEM + SEG + 16 zero-pad (17 tiles of 32)
#define NSH    256         // 16 segments * 16 heads

typedef __hip_bfloat16 bf16;
typedef __attribute__((ext_vector_type(8))) short short8;   // 8 bf16 = 4 VGPRs
typedef __attribute__((ext_vector_type(4))) float floatx4;  // MFMA C/D frag

__device__ __forceinline__ short8 ld_frag(const bf16* p) {
    return *(const short8*)p;
}
__device__ __forceinline__ floatx4 mfma16(short8 a, short8 b, floatx4 c) {
    return __builtin_amdgcn_mfma_f32_16x16x32_bf16(a, b, c, 0, 0, 0);
}
__device__ __forceinline__ void st_out(bf16* p, float v) { *p = __float2bfloat16(v); }
__device__ __forceinline__ void st_out(float* p, float v) { *p = v; }
// async global->LDS DMA, 16 B per lane; LDS dest must be wave base + lane*16
__device__ __forceinline__ void g2lds16(const bf16* g, bf16* l) {
    __builtin_amdgcn_global_load_lds((const __attribute__((address_space(1))) void*)g,
                                     (__attribute__((address_space(3))) void*)l, 16, 0, 0);
}

// ---------------- RMSNorm: fp32 in -> bf16 normalized ----------------
__global__ void rmsnorm_kernel(const float* __restrict__ x, const float* __restrict__ wgt,
                               bf16* __restrict__ xn) {
    int row = blockIdx.x;
    int tid = threadIdx.x;              // 256 threads, 4 floats each
    const float4* xr = (const float4*)(x + (long)row * DIM);
    float4 v = xr[tid];
    float ss = v.x * v.x + v.y * v.y + v.z * v.z + v.w * v.w;
    #pragma unroll
    for (int off = 32; off; off >>= 1) ss += __shfl_xor(ss, off);
    __shared__ float red[4];
    if ((tid & 63) == 0) red[tid >> 6] = ss;
    __syncthreads();
    float tot = red[0] + red[1] + red[2] + red[3];
    float sc = rsqrtf(tot * (1.0f / DIM) + 1.1920929e-07f);
    const float4* wr = (const float4*)wgt;
    float4 w4 = wr[tid];
    bf16* o = xn + (long)row * DIM + tid * 4;
    o[0] = __float2bfloat16(v.x * sc * w4.x);
    o[1] = __float2bfloat16(v.y * sc * w4.y);
    o[2] = __float2bfloat16(v.z * sc * w4.z);
    o[3] = __float2bfloat16(v.w * sc * w4.w);
}

// ------------- transpose + cast: fp32 [R][C] -> bf16 [C][R] ----------
__global__ void transpose_cast(const float* __restrict__ in, bf16* __restrict__ out,
                               int R, int C) {
    __shared__ float tile[32][33];
    int c0 = blockIdx.x * 32, r0 = blockIdx.y * 32;
    int tx = threadIdx.x, ty = threadIdx.y;      // (32,8)
    #pragma unroll
    for (int i = 0; i < 4; i++)
        tile[ty + i * 8][tx] = in[(long)(r0 + ty + i * 8) * C + c0 + tx];
    __syncthreads();
    #pragma unroll
    for (int i = 0; i < 4; i++)
        out[(long)(c0 + ty + i * 8) * R + r0 + tx] = __float2bfloat16(tile[tx][ty + i * 8]);
}

// ------- GEMM: C[M][N] = A[M][K] * Bt[N][K]^T, bf16 in, OT out -------
// BK=64, async LDS staging, XOR-swizzled LDS layout:
//   logical (row r, 16B-chunk c) lives at LDS slot r*64 + (c^(r&7))*8 elements.
//   DMA dest is lane-linear, so the permutation is applied to the GLOBAL src.
template <typename OT>
__global__ __launch_bounds__(256)
void gemm_bt(const bf16* __restrict__ A, const bf16* __restrict__ Bt,
             OT* __restrict__ C, int M, int N, int K) {
    __shared__ __align__(16) bf16 As[128 * 64];   // 16 KB
    __shared__ __align__(16) bf16 Bs[128 * 64];   // 16 KB
    const int tid = threadIdx.x;
    const int wv = tid >> 6;
    const int lane = tid & 63;
    const int quad = lane >> 4, l15 = lane & 15;
    const int wm = (wv >> 1) * 64, wn = (wv & 1) * 64;
    const int bm = blockIdx.x, bn = blockIdx.y;

    // staging: 4 issues per matrix; issue i covers rows i*32 + (tid>>3)
    const int srow = tid >> 3;                        // 0..31
    const int sgch = (tid & 7) ^ (srow & 7);          // logical chunk fetched into slot tid&7
    const bf16* Ag = A + (long)(bm * 128 + srow) * K + sgch * 8;
    const bf16* Bg = Bt + (long)(bn * 128 + srow) * K + sgch * 8;
    const long row32 = (long)32 * K;

    // reader: logical chunk kk*4+quad at row R -> slot (kk*4+quad)^(R&7), R&7 == l15&7
    const int rx0 = ((0 + quad) ^ (l15 & 7)) * 8;
    const int rx1 = ((4 + quad) ^ (l15 & 7)) * 8;

    floatx4 acc[4][4] = {};

    for (int k0 = 0; k0 < K; k0 += 64) {
        __syncthreads();                 // prior iter's ds_reads done before DMA overwrite
        #pragma unroll
        for (int i = 0; i < 4; i++) {
            g2lds16(Ag + i * row32 + k0, As + i * 2048 + tid * 8);
            g2lds16(Bg + i * row32 + k0, Bs + i * 2048 + tid * 8);
        }
        __syncthreads();                 // DMA landed
        #pragma unroll
        for (int kk = 0; kk < 2; kk++) {
            const int rx = kk ? rx1 : rx0;
            short8 af[4], bfr[4];
            #pragma unroll
            for (int i = 0; i < 4; i++) af[i] = ld_frag(&As[(wm + i * 16 + l15) * 64 + rx]);
            #pragma unroll
            for (int j = 0; j < 4; j++) bfr[j] = ld_frag(&Bs[(wn + j * 16 + l15) * 64 + rx]);
            #pragma unroll
            for (int i = 0; i < 4; i++)
                #pragma unroll
                for (int j = 0; j < 4; j++)
                    acc[i][j] = mfma16(af[i], bfr[j], acc[i][j]);
        }
    }
    #pragma unroll
    for (int i = 0; i < 4; i++)
        #pragma unroll
        for (int j = 0; j < 4; j++) {
            int row = bm * 128 + wm + i * 16 + quad * 4;
            int col = bn * 128 + wn + j * 16 + l15;
            #pragma unroll
            for (int r = 0; r < 4; r++)
                st_out(&C[(long)(row + r) * N + col], acc[i][j][r]);
        }
}

// ------------- pmem rows into kpad/vtpad + zero tail pad -------------
__global__ void fill_pmem_pad(const float* __restrict__ pmem, bf16* __restrict__ kpad,
                              bf16* __restrict__ vtpad) {
    int gid = blockIdx.x * 256 + threadIdx.x;
    int dh = gid & 63, j = (gid >> 6) & 15, sh = gid >> 10;
    int h = sh & 15;
    float kv = pmem[((0 * HEADS + h) * PMEMN + j) * DH + dh];
    float vv = pmem[((1 * HEADS + h) * PMEMN + j) * DH + dh];
    kpad[((long)sh * JPAD + j) * DH + dh] = __float2bfloat16(kv);
    vtpad[((long)sh * DH + dh) * JPAD + j] = __float2bfloat16(vv);
    kpad[((long)sh * JPAD + PMEMN + SEG + j) * DH + dh] = __float2bfloat16(0.0f);
    vtpad[((long)sh * DH + dh) * JPAD + PMEMN + SEG + j] = __float2bfloat16(0.0f);
}

// --- RoPE: q in place in qkv (pre-scaled by 2^-3, bf16-exact); k -> kpad ---
__global__ void rope_qk(bf16* __restrict__ qkv, bf16* __restrict__ kpad) {
    int pid = blockIdx.x * 256 + threadIdx.x;
    int pr = pid & 31;
    int h  = (pid >> 5) & 15;
    int t  = (pid >> 9) & 8191;
    int qk = pid >> 22;
    int s  = t & 511;
    float invf = __expf(-(float)pr * (9.210340371976184f / 32.0f));
    float ang = (float)s * invf;
    float sn, cs;
    __sincosf(ang, &sn, &cs);
    long base = (long)t * NQKV + qk * DIM + h * DH + 2 * pr;
    float x1 = __bfloat162float(qkv[base]);
    float x2 = __bfloat162float(qkv[base + 1]);
    float y1 = x1 * cs - x2 * sn;
    float y2 = x2 * cs + x1 * sn;
    if (qk == 0) {
        qkv[base]     = __float2bfloat16(y1 * 0.125f);   // fold DH^-0.5 into q (exact)
        qkv[base + 1] = __float2bfloat16(y2 * 0.125f);
    } else {
        int sh = (t >> 9) * HEADS + h;
        long kb = ((long)sh * JPAD + PMEMN + s) * DH + 2 * pr;
        kpad[kb]     = __float2bfloat16(y1);
        kpad[kb + 1] = __float2bfloat16(y2);
    }
}

// ------- v: write orig_v output fp32 (sh,s,dh) + transposed vtpad[sh][dh][16+s] -------
__global__ void v_copy(const bf16* __restrict__ qkv, float* __restrict__ origv,
                       bf16* __restrict__ vtpad) {
    int sh = blockIdx.y;
    int s0 = blockIdx.x * 64;
    int bw = sh >> 4, h = sh & 15;
    __shared__ bf16 tile[64][65];
    #pragma unroll
    for (int i = 0; i < 16; i++) {
        int idx = i * 256 + threadIdx.x;
        int sr = idx >> 6, dh = idx & 63;
        bf16 v = qkv[(long)(bw * SEG + s0 + sr) * NQKV + 2 * DIM + h * DH + dh];
        tile[sr][dh] = v;
        origv[((long)sh * SEG + s0 + sr) * DH + dh] = __bfloat162float(v);
    }
    __syncthreads();
    #pragma unroll
    for (int i = 0; i < 16; i++) {
        int idx = i * 256 + threadIdx.x;
        int dh = idx >> 6, sr = idx & 63;
        vtpad[((long)sh * DH + dh) * JPAD + PMEMN + s0 + sr] = tile[sr][dh];
    }
}

// ------- flash attention: 1 wave = 32 q rows; block shares K/V via LDS staging -------
// grid: 1024 blocks, id = qblk*NSH + sh. Uniform trip count per block (extra tiles
// are fully masked -> p=0, alpha=1: inert), so __syncthreads is legal.
__global__ __launch_bounds__(256, 3)
void flash_attn(const bf16* __restrict__ qkv, const bf16* __restrict__ kpad,
                const bf16* __restrict__ vtpad, bf16* __restrict__ attn_out) {
    const int bid = blockIdx.x;
    const int sh = bid & (NSH - 1);
    const int qblk = bid >> 8;
    const int tid = threadIdx.x;
    const int wv = tid >> 6;
    const int lane = tid & 63;
    const int quad = lane >> 4, l15 = lane & 15;
    const int qr0 = qblk * 128 + wv * 32;
    const int bw = sh >> 4, h = sh & 15;
    const int NT = (qblk * 128 + 143) / 32 + 1;   // block-uniform tile count

    __shared__ __align__(16) short pbuf[4][32 * 32];   // 8 KB, per-wave P tile
    __shared__ __align__(16) bf16 Ks[32 * 64];         // 4 KB  [j][dh], XOR-swizzled chunks
    __shared__ __align__(16) bf16 Vs[64 * 32];         // 4 KB  [dh][j]
    short* pb = pbuf[wv];

    const bf16* qr_g0 = qkv + (long)(bw * SEG + qr0 + l15) * NQKV + h * DH;
    const bf16* qr_g1 = qkv + (long)(bw * SEG + qr0 + 16 + l15) * NQKV + h * DH;
    short8 aq[2][2] = {{ld_frag(qr_g0 + quad * 8), ld_frag(qr_g0 + 32 + quad * 8)},
                       {ld_frag(qr_g1 + quad * 8), ld_frag(qr_g1 + 32 + quad * 8)}};

    float mrow[2][4], lrow[2][4];
    floatx4 o[2][4] = {};
    #pragma unroll
    for (int g = 0; g < 2; g++)
        #pragma unroll
        for (int r = 0; r < 4; r++) { mrow[g][r] = -1e30f; lrow[g][r] = 0.0f; }

    const bf16* kb = kpad + (long)sh * JPAD * DH;
    const bf16* vbp = vtpad + (long)sh * DH * JPAD;

    // K staging src (swizzled chunk), V staging src
    const int ksrow = tid >> 3;                       // j row 0..31
    const int kgch = (tid & 7) ^ (ksrow & 7);
    const bf16* kg = kb + (long)ksrow * DH + kgch * 8;
    const bf16* vg = vbp + (long)(tid >> 2) * JPAD + (tid & 3) * 8;
    // K reader swizzle: chunk kk*4+quad at row R -> slot ^(R&7), R&7 == l15&7
    const int rx0 = ((0 + quad) ^ (l15 & 7)) * 8;
    const int rx1 = ((4 + quad) ^ (l15 & 7)) * 8;

    for (int jt = 0; jt < NT; ++jt) {
        const int j0 = jt * 32;
        __syncthreads();                 // prev tile's LDS reads done
        g2lds16(kg + (long)j0 * DH, Ks + tid * 8);
        g2lds16(vg + j0,            Vs + tid * 8);
        __syncthreads();                 // DMA landed

        short8 k00 = ld_frag(&Ks[l15 * 64 + rx0]);
        short8 k01 = ld_frag(&Ks[l15 * 64 + rx1]);
        short8 k10 = ld_frag(&Ks[(16 + l15) * 64 + rx0]);
        short8 k11 = ld_frag(&Ks[(16 + l15) * 64 + rx1]);
        short8 bv[4];
        #pragma unroll
        for (int n = 0; n < 4; n++)
            bv[n] = ld_frag(&Vs[(n * 16 + l15) * 32 + quad * 8]);

        float alpha[2][4];
        #pragma unroll
        for (int g = 0; g < 2; g++) {
            floatx4 s0 = {}, s1 = {};
            s0 = mfma16(aq[g][0], k00, s0);
            s0 = mfma16(aq[g][1], k01, s0);
            s1 = mfma16(aq[g][0], k10, s1);
            s1 = mfma16(aq[g][1], k11, s1);
            #pragma unroll
            for (int r = 0; r < 4; r++) {
                int qi = qr0 + g * 16 + quad * 4 + r;
                int ja = j0 + l15;
                int jb = j0 + 16 + l15;
                float va  = ((ja < PMEMN) || (ja - PMEMN <= qi)) ? s0[r] : -1e30f;
                float vb2 = ((jb < PMEMN) || (jb - PMEMN <= qi)) ? s1[r] : -1e30f;
                float rm = fmaxf(va, vb2);
                #pragma unroll
                for (int off = 1; off < 16; off <<= 1) rm = fmaxf(rm, __shfl_xor(rm, off));
                float mn = fmaxf(mrow[g][r], rm);
                alpha[g][r] = __expf(mrow[g][r] - mn);
                mrow[g][r] = mn;
                float p0 = __expf(va - mn);
                float p1 = __expf(vb2 - mn);
                float rs = p0 + p1;
                #pragma unroll
                for (int off = 1; off < 16; off <<= 1) rs += __shfl_xor(rs, off);
                lrow[g][r] = lrow[g][r] * alpha[g][r] + rs;
                pb[(g * 16 + quad * 4 + r) * 32 + l15]      = __builtin_bit_cast(short, __float2bfloat16(p0));
                pb[(g * 16 + quad * 4 + r) * 32 + 16 + l15] = __builtin_bit_cast(short, __float2bfloat16(p1));
            }
        }
        __asm__ volatile("" ::: "memory");
        short8 pa0, pa1;
        __builtin_memcpy(&pa0, &pb[l15 * 32 + quad * 8], 16);
        __builtin_memcpy(&pa1, &pb[(16 + l15) * 32 + quad * 8], 16);
        __asm__ volatile("" ::: "memory");
        #pragma unroll
        for (int n = 0; n < 4; n++) {
            #pragma unroll
            for (int r = 0; r < 4; r++) { o[0][n][r] *= alpha[0][r]; o[1][n][r] *= alpha[1][r]; }
            o[0][n] = mfma16(pa0, bv[n], o[0][n]);
            o[1][n] = mfma16(pa1, bv[n], o[1][n]);
        }
    }
    #pragma unroll
    for (int g = 0; g < 2; g++) {
        bf16* orow = attn_out + (long)(bw * SEG + qr0 + g * 16 + quad * 4) * DIM + h * DH;
        #pragma unroll
        for (int r = 0; r < 4; r++) {
            float inv = 1.0f / lrow[g][r];
            #pragma unroll
            for (int n = 0; n < 4; n++)
                orow[(long)r * DIM + n * 16 + l15] = __float2bfloat16(o[g][n][r] * inv);
        }
    }
}

extern "C" void kernel_launch(void* const* d_in, const int* in_sizes, int n_in,
                              void* d_out, int out_size, void* d_ws, size_t ws_size,
                              hipStream_t stream) {
    const float* seq    = (const float*)d_in[0];
    const float* norm_w = (const float*)d_in[1];
    const float* w_qkv  = (const float*)d_in[2];
    const float* w_out  = (const float*)d_in[3];
    const float* pmem   = (const float*)d_in[4];
    // Reference outputs are FLOAT32: d_out = [out, orig_v] fp32.
    float* out   = (float*)d_out;
    float* origv = out + (long)TOK * DIM;

    char* p = (char*)d_ws;
    bf16* xn     = (bf16*)p; p += (long)TOK * DIM * 2;
    bf16* wqkvT  = (bf16*)p; p += (long)NQKV * DIM * 2;
    bf16* woutT  = (bf16*)p; p += (long)DIM * DIM * 2;
    bf16* qkv    = (bf16*)p; p += (long)TOK * NQKV * 2;
    bf16* kpadb  = (bf16*)p; p += (long)NSH * JPAD * DH * 2;
    bf16* vtpadb = (bf16*)p; p += (long)NSH * DH * JPAD * 2;
    bf16* attno  = xn;   // xn dead after QKV GEMM

    rmsnorm_kernel<<<TOK, 256, 0, stream>>>(seq, norm_w, xn);
    transpose_cast<<<dim3(NQKV / 32, DIM / 32), dim3(32, 8), 0, stream>>>(w_qkv, wqkvT, DIM, NQKV);
    transpose_cast<<<dim3(DIM / 32, DIM / 32), dim3(32, 8), 0, stream>>>(w_out, woutT, DIM, DIM);
    gemm_bt<bf16><<<dim3(TOK / 128, NQKV / 128), 256, 0, stream>>>(xn, wqkvT, qkv, TOK, NQKV, DIM);
    fill_pmem_pad<<<(NSH * PMEMN * DH) / 256, 256, 0, stream>>>(pmem, kpadb, vtpadb);
    rope_qk<<<(2L * TOK * HEADS * 32) / 256, 256, 0, stream>>>(qkv, kpadb);
    v_copy<<<dim3(SEG / 64, NSH), 256, 0, stream>>>(qkv, origv, vtpadb);
    flash_attn<<<4 * NSH, 256, 0, stream>>>(qkv, kpadb, vtpadb, attno);
    gemm_bt<float><<<dim3(TOK / 128, DIM / 128), 256, 0, stream>>>(attno, woutT, out, TOK, DIM, DIM);
}

// Round 8
// 266.367 us; speedup vs baseline: 7.1735x; 1.0574x over previous
//
#include <hip/hip_runtime.h>
#include <hip/hip_bf16.h>

#define DIM    1024
#define HEADS  16
#define DH     64
#define SEG    512
#define PMEMN  16
#define TOK    8192        // 2*4096 tokens = 16 segments * 512
#define NQKV   3072
#define JPAD   544         // PMEM + SEG + 16 zero-pad (17 tiles of 32)
#define NSH    256         // 16 segments * 16 heads

typedef __hip_bfloat16 bf16;
typedef __attribute__((ext_vector_type(8))) short short8;   // 8 bf16 = 4 VGPRs
typedef __attribute__((ext_vector_type(4))) float floatx4;  // MFMA C/D frag

__device__ __forceinline__ short8 ld_frag(const bf16* p) {
    return *(const short8*)p;
}
__device__ __forceinline__ floatx4 mfma16(short8 a, short8 b, floatx4 c) {
    return __builtin_amdgcn_mfma_f32_16x16x32_bf16(a, b, c, 0, 0, 0);
}
__device__ __forceinline__ void st_out(bf16* p, float v) { *p = __float2bfloat16(v); }
__device__ __forceinline__ void st_out(float* p, float v) { *p = v; }
// async global->LDS DMA, 16 B per lane; LDS dest must be wave base + lane*16
__device__ __forceinline__ void g2lds16(const bf16* g, bf16* l) {
    __builtin_amdgcn_global_load_lds((const __attribute__((address_space(1))) void*)g,
                                     (__attribute__((address_space(3))) void*)l, 16, 0, 0);
}

// ---------------- RMSNorm: fp32 in -> bf16 normalized ----------------
__global__ void rmsnorm_kernel(const float* __restrict__ x, const float* __restrict__ wgt,
                               bf16* __restrict__ xn) {
    int row = blockIdx.x;
    int tid = threadIdx.x;              // 256 threads, 4 floats each
    const float4* xr = (const float4*)(x + (long)row * DIM);
    float4 v = xr[tid];
    float ss = v.x * v.x + v.y * v.y + v.z * v.z + v.w * v.w;
    #pragma unroll
    for (int off = 32; off; off >>= 1) ss += __shfl_xor(ss, off);
    __shared__ float red[4];
    if ((tid & 63) == 0) red[tid >> 6] = ss;
    __syncthreads();
    float tot = red[0] + red[1] + red[2] + red[3];
    float sc = rsqrtf(tot * (1.0f / DIM) + 1.1920929e-07f);
    const float4* wr = (const float4*)wgt;
    float4 w4 = wr[tid];
    bf16* o = xn + (long)row * DIM + tid * 4;
    o[0] = __float2bfloat16(v.x * sc * w4.x);
    o[1] = __float2bfloat16(v.y * sc * w4.y);
    o[2] = __float2bfloat16(v.z * sc * w4.z);
    o[3] = __float2bfloat16(v.w * sc * w4.w);
}

// ------------- transpose + cast: fp32 [R][C] -> bf16 [C][R] ----------
__global__ void transpose_cast(const float* __restrict__ in, bf16* __restrict__ out,
                               int R, int C) {
    __shared__ float tile[32][33];
    int c0 = blockIdx.x * 32, r0 = blockIdx.y * 32;
    int tx = threadIdx.x, ty = threadIdx.y;      // (32,8)
    #pragma unroll
    for (int i = 0; i < 4; i++)
        tile[ty + i * 8][tx] = in[(long)(r0 + ty + i * 8) * C + c0 + tx];
    __syncthreads();
    #pragma unroll
    for (int i = 0; i < 4; i++)
        out[(long)(c0 + ty + i * 8) * R + r0 + tx] = __float2bfloat16(tile[tx][ty + i * 8]);
}

// ------- GEMM: C[M][N] = A[M][K] * Bt[N][K]^T, bf16 in, OT out -------
// BK=64, async LDS staging, XOR-swizzled LDS layout.
template <typename OT>
__global__ __launch_bounds__(256)
void gemm_bt(const bf16* __restrict__ A, const bf16* __restrict__ Bt,
             OT* __restrict__ C, int M, int N, int K) {
    __shared__ __align__(16) bf16 As[128 * 64];   // 16 KB
    __shared__ __align__(16) bf16 Bs[128 * 64];   // 16 KB
    const int tid = threadIdx.x;
    const int wv = tid >> 6;
    const int lane = tid & 63;
    const int quad = lane >> 4, l15 = lane & 15;
    const int wm = (wv >> 1) * 64, wn = (wv & 1) * 64;
    const int bm = blockIdx.x, bn = blockIdx.y;

    const int srow = tid >> 3;                        // 0..31
    const int sgch = (tid & 7) ^ (srow & 7);
    const bf16* Ag = A + (long)(bm * 128 + srow) * K + sgch * 8;
    const bf16* Bg = Bt + (long)(bn * 128 + srow) * K + sgch * 8;
    const long row32 = (long)32 * K;

    const int rx0 = ((0 + quad) ^ (l15 & 7)) * 8;
    const int rx1 = ((4 + quad) ^ (l15 & 7)) * 8;

    floatx4 acc[4][4] = {};

    for (int k0 = 0; k0 < K; k0 += 64) {
        __syncthreads();
        #pragma unroll
        for (int i = 0; i < 4; i++) {
            g2lds16(Ag + i * row32 + k0, As + i * 2048 + tid * 8);
            g2lds16(Bg + i * row32 + k0, Bs + i * 2048 + tid * 8);
        }
        __syncthreads();
        #pragma unroll
        for (int kk = 0; kk < 2; kk++) {
            const int rx = kk ? rx1 : rx0;
            short8 af[4], bfr[4];
            #pragma unroll
            for (int i = 0; i < 4; i++) af[i] = ld_frag(&As[(wm + i * 16 + l15) * 64 + rx]);
            #pragma unroll
            for (int j = 0; j < 4; j++) bfr[j] = ld_frag(&Bs[(wn + j * 16 + l15) * 64 + rx]);
            #pragma unroll
            for (int i = 0; i < 4; i++)
                #pragma unroll
                for (int j = 0; j < 4; j++)
                    acc[i][j] = mfma16(af[i], bfr[j], acc[i][j]);
        }
    }
    #pragma unroll
    for (int i = 0; i < 4; i++)
        #pragma unroll
        for (int j = 0; j < 4; j++) {
            int row = bm * 128 + wm + i * 16 + quad * 4;
            int col = bn * 128 + wn + j * 16 + l15;
            #pragma unroll
            for (int r = 0; r < 4; r++)
                st_out(&C[(long)(row + r) * N + col], acc[i][j][r]);
        }
}

// ------------- pmem rows into kpad/vtpad + zero tail pad -------------
__global__ void fill_pmem_pad(const float* __restrict__ pmem, bf16* __restrict__ kpad,
                              bf16* __restrict__ vtpad) {
    int gid = blockIdx.x * 256 + threadIdx.x;
    int dh = gid & 63, j = (gid >> 6) & 15, sh = gid >> 10;
    int h = sh & 15;
    float kv = pmem[((0 * HEADS + h) * PMEMN + j) * DH + dh];
    float vv = pmem[((1 * HEADS + h) * PMEMN + j) * DH + dh];
    kpad[((long)sh * JPAD + j) * DH + dh] = __float2bfloat16(kv);
    vtpad[((long)sh * DH + dh) * JPAD + j] = __float2bfloat16(vv);
    kpad[((long)sh * JPAD + PMEMN + SEG + j) * DH + dh] = __float2bfloat16(0.0f);
    vtpad[((long)sh * DH + dh) * JPAD + PMEMN + SEG + j] = __float2bfloat16(0.0f);
}

// --- RoPE: q in place in qkv (pre-scaled by 2^-3, bf16-exact); k -> kpad ---
__global__ void rope_qk(bf16* __restrict__ qkv, bf16* __restrict__ kpad) {
    int pid = blockIdx.x * 256 + threadIdx.x;
    int pr = pid & 31;
    int h  = (pid >> 5) & 15;
    int t  = (pid >> 9) & 8191;
    int qk = pid >> 22;
    int s  = t & 511;
    float invf = __expf(-(float)pr * (9.210340371976184f / 32.0f));
    float ang = (float)s * invf;
    float sn, cs;
    __sincosf(ang, &sn, &cs);
    long base = (long)t * NQKV + qk * DIM + h * DH + 2 * pr;
    float x1 = __bfloat162float(qkv[base]);
    float x2 = __bfloat162float(qkv[base + 1]);
    float y1 = x1 * cs - x2 * sn;
    float y2 = x2 * cs + x1 * sn;
    if (qk == 0) {
        qkv[base]     = __float2bfloat16(y1 * 0.125f);   // fold DH^-0.5 into q (exact)
        qkv[base + 1] = __float2bfloat16(y2 * 0.125f);
    } else {
        int sh = (t >> 9) * HEADS + h;
        long kb = ((long)sh * JPAD + PMEMN + s) * DH + 2 * pr;
        kpad[kb]     = __float2bfloat16(y1);
        kpad[kb + 1] = __float2bfloat16(y2);
    }
}

// ------- v: write orig_v output fp32 (sh,s,dh) + transposed vtpad[sh][dh][16+s] -------
__global__ void v_copy(const bf16* __restrict__ qkv, float* __restrict__ origv,
                       bf16* __restrict__ vtpad) {
    int sh = blockIdx.y;
    int s0 = blockIdx.x * 64;
    int bw = sh >> 4, h = sh & 15;
    __shared__ bf16 tile[64][65];
    #pragma unroll
    for (int i = 0; i < 16; i++) {
        int idx = i * 256 + threadIdx.x;
        int sr = idx >> 6, dh = idx & 63;
        bf16 v = qkv[(long)(bw * SEG + s0 + sr) * NQKV + 2 * DIM + h * DH + dh];
        tile[sr][dh] = v;
        origv[((long)sh * SEG + s0 + sr) * DH + dh] = __bfloat162float(v);
    }
    __syncthreads();
    #pragma unroll
    for (int i = 0; i < 16; i++) {
        int idx = i * 256 + threadIdx.x;
        int dh = idx >> 6, sr = idx & 63;
        vtpad[((long)sh * DH + dh) * JPAD + PMEMN + s0 + sr] = tile[sr][dh];
    }
}

// ------- flash attention v3: 1 wave = 32 q rows, NO block barriers in K-loop -------
// Direct per-wave K/V fragment loads (L2-shared), K software-pipelined one tile
// ahead, V issued at loop top and consumed after softmax. Row-sum l computed by
// an extra ones-column MFMA (same alpha recurrence as O) - no sum shuffles.
// grid: 1024 blocks, id = qblk*NSH + sh (same-sh blocks share an XCD's L2).
__global__ __launch_bounds__(256, 3)
void flash_attn(const bf16* __restrict__ qkv, const bf16* __restrict__ kpad,
                const bf16* __restrict__ vtpad, bf16* __restrict__ attn_out) {
    const int bid = blockIdx.x;
    const int sh = bid & (NSH - 1);
    const int qblk = bid >> 8;
    const int wv = threadIdx.x >> 6;
    const int lane = threadIdx.x & 63;
    const int quad = lane >> 4, l15 = lane & 15;
    const int qr0 = qblk * 128 + wv * 32;
    const int bw = sh >> 4, h = sh & 15;

    __shared__ __align__(16) short pbuf[4][32 * 32];   // per-wave P tile
    short* pb = pbuf[wv];

    const bf16* qr_g0 = qkv + (long)(bw * SEG + qr0 + l15) * NQKV + h * DH;
    const bf16* qr_g1 = qkv + (long)(bw * SEG + qr0 + 16 + l15) * NQKV + h * DH;
    short8 aq[2][2] = {{ld_frag(qr_g0 + quad * 8), ld_frag(qr_g0 + 32 + quad * 8)},
                       {ld_frag(qr_g1 + quad * 8), ld_frag(qr_g1 + 32 + quad * 8)}};

    // ones B-fragment: B[k][0]=1 -> D[:,0] = row-sum of P
    const short bf16one = (short)0x3F80;
    short8 onesB;
    #pragma unroll
    for (int i = 0; i < 8; i++) onesB[i] = (l15 == 0) ? bf16one : (short)0;

    float mrow[2][4];
    floatx4 o[2][4] = {};
    floatx4 lac[2] = {};                 // l accumulator (valid in lanes l15==0)
    #pragma unroll
    for (int g = 0; g < 2; g++)
        #pragma unroll
        for (int r = 0; r < 4; r++) mrow[g][r] = -1e30f;

    const bf16* kb = kpad + (long)sh * JPAD * DH;
    const bf16* vbp = vtpad + (long)sh * DH * JPAD;

    const int ntiles = (qr0 + 47) / 32 + 1;   // causal: j0 <= qr0+31+16

    // prefetch K tile 0
    short8 kf[4];
    {
        const bf16* kr0 = kb + (long)l15 * DH;
        const bf16* kr1 = kb + (long)(16 + l15) * DH;
        kf[0] = ld_frag(kr0 + quad * 8);  kf[1] = ld_frag(kr0 + 32 + quad * 8);
        kf[2] = ld_frag(kr1 + quad * 8);  kf[3] = ld_frag(kr1 + 32 + quad * 8);
    }

    for (int jt = 0; jt < ntiles; ++jt) {
        const int j0 = jt * 32;
        // issue V loads for current tile (used after softmax -> latency hidden)
        short8 bv[4];
        #pragma unroll
        for (int n = 0; n < 4; n++)
            bv[n] = ld_frag(vbp + (long)(n * 16 + l15) * JPAD + j0 + quad * 8);

        // QK with prefetched K
        floatx4 sc[2][2];
        #pragma unroll
        for (int g = 0; g < 2; g++) {
            sc[g][0] = mfma16(aq[g][1], kf[1], mfma16(aq[g][0], kf[0], floatx4{}));
            sc[g][1] = mfma16(aq[g][1], kf[3], mfma16(aq[g][0], kf[2], floatx4{}));
        }
        // prefetch K for next tile (clamped on last iter; wave-uniform)
        {
            const int jn = (jt + 1 < ntiles) ? j0 + 32 : j0;
            const bf16* kr0 = kb + (long)(jn + l15) * DH;
            const bf16* kr1 = kb + (long)(jn + 16 + l15) * DH;
            kf[0] = ld_frag(kr0 + quad * 8);  kf[1] = ld_frag(kr0 + 32 + quad * 8);
            kf[2] = ld_frag(kr1 + quad * 8);  kf[3] = ld_frag(kr1 + 32 + quad * 8);
        }

        float alpha[2][4];
        #pragma unroll
        for (int g = 0; g < 2; g++) {
            #pragma unroll
            for (int r = 0; r < 4; r++) {
                int qi = qr0 + g * 16 + quad * 4 + r;
                int ja = j0 + l15;
                int jb = j0 + 16 + l15;
                float va  = ((ja < PMEMN) || (ja - PMEMN <= qi)) ? sc[g][0][r] : -1e30f;
                float vb2 = ((jb < PMEMN) || (jb - PMEMN <= qi)) ? sc[g][1][r] : -1e30f;
                float rm = fmaxf(va, vb2);
                #pragma unroll
                for (int off = 1; off < 16; off <<= 1) rm = fmaxf(rm, __shfl_xor(rm, off));
                float mn = fmaxf(mrow[g][r], rm);
                alpha[g][r] = __expf(mrow[g][r] - mn);
                mrow[g][r] = mn;
                float p0 = __expf(va - mn);
                float p1 = __expf(vb2 - mn);
                pb[(g * 16 + quad * 4 + r) * 32 + l15]      = __builtin_bit_cast(short, __float2bfloat16(p0));
                pb[(g * 16 + quad * 4 + r) * 32 + 16 + l15] = __builtin_bit_cast(short, __float2bfloat16(p1));
            }
        }
        __asm__ volatile("" ::: "memory");
        short8 pa0, pa1;
        __builtin_memcpy(&pa0, &pb[l15 * 32 + quad * 8], 16);
        __builtin_memcpy(&pa1, &pb[(16 + l15) * 32 + quad * 8], 16);
        __asm__ volatile("" ::: "memory");
        // rescale o and l, then accumulate PV and row-sum
        #pragma unroll
        for (int r = 0; r < 4; r++) { lac[0][r] *= alpha[0][r]; lac[1][r] *= alpha[1][r]; }
        lac[0] = mfma16(pa0, onesB, lac[0]);
        lac[1] = mfma16(pa1, onesB, lac[1]);
        #pragma unroll
        for (int n = 0; n < 4; n++) {
            #pragma unroll
            for (int r = 0; r < 4; r++) { o[0][n][r] *= alpha[0][r]; o[1][n][r] *= alpha[1][r]; }
            o[0][n] = mfma16(pa0, bv[n], o[0][n]);
            o[1][n] = mfma16(pa1, bv[n], o[1][n]);
        }
    }
    // recover l (lives in lanes l15==0 of each quad), normalize, store
    #pragma unroll
    for (int g = 0; g < 2; g++) {
        bf16* orow = attn_out + (long)(bw * SEG + qr0 + g * 16 + quad * 4) * DIM + h * DH;
        #pragma unroll
        for (int r = 0; r < 4; r++) {
            float lsum = __shfl(lac[g][r], (lane & 48));   // lane quad*16
            float inv = 1.0f / lsum;
            #pragma unroll
            for (int n = 0; n < 4; n++)
                orow[(long)r * DIM + n * 16 + l15] = __float2bfloat16(o[g][n][r] * inv);
        }
    }
}

extern "C" void kernel_launch(void* const* d_in, const int* in_sizes, int n_in,
                              void* d_out, int out_size, void* d_ws, size_t ws_size,
                              hipStream_t stream) {
    const float* seq    = (const float*)d_in[0];
    const float* norm_w = (const float*)d_in[1];
    const float* w_qkv  = (const float*)d_in[2];
    const float* w_out  = (const float*)d_in[3];
    const float* pmem   = (const float*)d_in[4];
    // Reference outputs are FLOAT32: d_out = [out, orig_v] fp32.
    float* out   = (float*)d_out;
    float* origv = out + (long)TOK * DIM;

    char* p = (char*)d_ws;
    bf16* xn     = (bf16*)p; p += (long)TOK * DIM * 2;
    bf16* wqkvT  = (bf16*)p; p += (long)NQKV * DIM * 2;
    bf16* woutT  = (bf16*)p; p += (long)DIM * DIM * 2;
    bf16* qkv    = (bf16*)p; p += (long)TOK * NQKV * 2;
    bf16* kpadb  = (bf16*)p; p += (long)NSH * JPAD * DH * 2;
    bf16* vtpadb = (bf16*)p; p += (long)NSH * DH * JPAD * 2;
    bf16* attno  = xn;   // xn dead after QKV GEMM

    rmsnorm_kernel<<<TOK, 256, 0, stream>>>(seq, norm_w, xn);
    transpose_cast<<<dim3(NQKV / 32, DIM / 32), dim3(32, 8), 0, stream>>>(w_qkv, wqkvT, DIM, NQKV);
    transpose_cast<<<dim3(DIM / 32, DIM / 32), dim3(32, 8), 0, stream>>>(w_out, woutT, DIM, DIM);
    gemm_bt<bf16><<<dim3(TOK / 128, NQKV / 128), 256, 0, stream>>>(xn, wqkvT, qkv, TOK, NQKV, DIM);
    fill_pmem_pad<<<(NSH * PMEMN * DH) / 256, 256, 0, stream>>>(pmem, kpadb, vtpadb);
    rope_qk<<<(2L * TOK * HEADS * 32) / 256, 256, 0, stream>>>(qkv, kpadb);
    v_copy<<<dim3(SEG / 64, NSH), 256, 0, stream>>>(qkv, origv, vtpadb);
    flash_attn<<<4 * NSH, 256, 0, stream>>>(qkv, kpadb, vtpadb, attno);
    gemm_bt<float><<<dim3(TOK / 128, DIM / 128), 256, 0, stream>>>(attno, woutT, out, TOK, DIM, DIM);
}

// Round 9
// 243.266 us; speedup vs baseline: 7.8547x; 1.0950x over previous
//
#include <hip/hip_runtime.h>
#include <hip/hip_bf16.h>

#define DIM    1024
#define HEADS  16
#define DH     64
#define SEG    512
#define PMEMN  16
#define TOK    8192        // 2*4096 tokens = 16 segments * 512
#define NQKV   3072
#define JPAD   544         // PMEM + SEG + 16 zero-pad (17 tiles of 32)
#define NSH    256         // 16 segments * 16 heads

typedef __hip_bfloat16 bf16;
typedef __attribute__((ext_vector_type(8))) short short8;   // 8 bf16 = 4 VGPRs
typedef __attribute__((ext_vector_type(4))) float floatx4;  // MFMA C/D frag

__device__ __forceinline__ short8 ld_frag(const bf16* p) {
    return *(const short8*)p;
}
__device__ __forceinline__ floatx4 mfma16(short8 a, short8 b, floatx4 c) {
    return __builtin_amdgcn_mfma_f32_16x16x32_bf16(a, b, c, 0, 0, 0);
}
__device__ __forceinline__ void st_out(bf16* p, float v) { *p = __float2bfloat16(v); }
__device__ __forceinline__ void st_out(float* p, float v) { *p = v; }
// async global->LDS DMA, 16 B per lane; LDS dest must be wave base + lane*16
__device__ __forceinline__ void g2lds16(const bf16* g, bf16* l) {
    __builtin_amdgcn_global_load_lds((const __attribute__((address_space(1))) void*)g,
                                     (__attribute__((address_space(3))) void*)l, 16, 0, 0);
}

// ---------------- RMSNorm: fp32 in -> bf16 normalized ----------------
__global__ void rmsnorm_kernel(const float* __restrict__ x, const float* __restrict__ wgt,
                               bf16* __restrict__ xn) {
    int row = blockIdx.x;
    int tid = threadIdx.x;              // 256 threads, 4 floats each
    const float4* xr = (const float4*)(x + (long)row * DIM);
    float4 v = xr[tid];
    float ss = v.x * v.x + v.y * v.y + v.z * v.z + v.w * v.w;
    #pragma unroll
    for (int off = 32; off; off >>= 1) ss += __shfl_xor(ss, off);
    __shared__ float red[4];
    if ((tid & 63) == 0) red[tid >> 6] = ss;
    __syncthreads();
    float tot = red[0] + red[1] + red[2] + red[3];
    float sc = rsqrtf(tot * (1.0f / DIM) + 1.1920929e-07f);
    const float4* wr = (const float4*)wgt;
    float4 w4 = wr[tid];
    bf16* o = xn + (long)row * DIM + tid * 4;
    o[0] = __float2bfloat16(v.x * sc * w4.x);
    o[1] = __float2bfloat16(v.y * sc * w4.y);
    o[2] = __float2bfloat16(v.z * sc * w4.z);
    o[3] = __float2bfloat16(v.w * sc * w4.w);
}

// ---- merged transpose + cast: wqkv [1024][3072] and wout [1024][1024] -> bf16 [C][R] ----
__global__ void transpose_w2(const float* __restrict__ wqkv, const float* __restrict__ wout,
                             bf16* __restrict__ wqkvT, bf16* __restrict__ woutT) {
    __shared__ float tile[32][33];
    int bx = blockIdx.x;
    const float* in; bf16* out; int C, c0;
    if (bx < 96) { in = wqkv; out = wqkvT; C = NQKV; c0 = bx * 32; }
    else         { in = wout; out = woutT; C = DIM;  c0 = (bx - 96) * 32; }
    const int R = DIM;
    int r0 = blockIdx.y * 32;
    int tx = threadIdx.x, ty = threadIdx.y;      // (32,8)
    #pragma unroll
    for (int i = 0; i < 4; i++)
        tile[ty + i * 8][tx] = in[(long)(r0 + ty + i * 8) * C + c0 + tx];
    __syncthreads();
    #pragma unroll
    for (int i = 0; i < 4; i++)
        out[(long)(c0 + ty + i * 8) * R + r0 + tx] = __float2bfloat16(tile[tx][ty + i * 8]);
}

// ------- plain GEMM (out-projection): C[M][N] = A[M][K]*Bt[N][K]^T, BK=64, swizzled -------
template <typename OT>
__global__ __launch_bounds__(256)
void gemm_bt(const bf16* __restrict__ A, const bf16* __restrict__ Bt,
             OT* __restrict__ C, int M, int N, int K) {
    __shared__ __align__(16) bf16 As[128 * 64];
    __shared__ __align__(16) bf16 Bs[128 * 64];
    const int tid = threadIdx.x;
    const int wv = tid >> 6;
    const int lane = tid & 63;
    const int quad = lane >> 4, l15 = lane & 15;
    const int wm = (wv >> 1) * 64, wn = (wv & 1) * 64;
    const int bm = blockIdx.x, bn = blockIdx.y;

    const int srow = tid >> 3;
    const int sgch = (tid & 7) ^ (srow & 7);
    const bf16* Ag = A + (long)(bm * 128 + srow) * K + sgch * 8;
    const bf16* Bg = Bt + (long)(bn * 128 + srow) * K + sgch * 8;
    const long row32 = (long)32 * K;

    const int rx0 = ((0 + quad) ^ (l15 & 7)) * 8;
    const int rx1 = ((4 + quad) ^ (l15 & 7)) * 8;

    floatx4 acc[4][4] = {};

    for (int k0 = 0; k0 < K; k0 += 64) {
        __syncthreads();
        #pragma unroll
        for (int i = 0; i < 4; i++) {
            g2lds16(Ag + i * row32 + k0, As + i * 2048 + tid * 8);
            g2lds16(Bg + i * row32 + k0, Bs + i * 2048 + tid * 8);
        }
        __syncthreads();
        #pragma unroll
        for (int kk = 0; kk < 2; kk++) {
            const int rx = kk ? rx1 : rx0;
            short8 af[4], bfr[4];
            #pragma unroll
            for (int i = 0; i < 4; i++) af[i] = ld_frag(&As[(wm + i * 16 + l15) * 64 + rx]);
            #pragma unroll
            for (int j = 0; j < 4; j++) bfr[j] = ld_frag(&Bs[(wn + j * 16 + l15) * 64 + rx]);
            #pragma unroll
            for (int i = 0; i < 4; i++)
                #pragma unroll
                for (int j = 0; j < 4; j++)
                    acc[i][j] = mfma16(af[i], bfr[j], acc[i][j]);
        }
    }
    #pragma unroll
    for (int i = 0; i < 4; i++)
        #pragma unroll
        for (int j = 0; j < 4; j++) {
            int row = bm * 128 + wm + i * 16 + quad * 4;
            int col = bn * 128 + wn + j * 16 + l15;
            #pragma unroll
            for (int r = 0; r < 4; r++)
                st_out(&C[(long)(row + r) * N + col], acc[i][j][r]);
        }
}

// ------- QKV GEMM with fused epilogue: rope(q)->qbuf, rope(k)->kpad, v->origv+vtpad -------
__global__ __launch_bounds__(256)
void gemm_qkv_ep(const bf16* __restrict__ A, const bf16* __restrict__ Bt,
                 bf16* __restrict__ qbuf, bf16* __restrict__ kpad,
                 bf16* __restrict__ vtpad, float* __restrict__ origv) {
    const int K = DIM, N = NQKV;
    __shared__ __align__(16) bf16 SM[128 * 136];   // 34816 B; K-loop uses first 32 KB
    bf16* As = SM;
    bf16* Bs = SM + 128 * 64;
    const int tid = threadIdx.x;
    const int wv = tid >> 6;
    const int lane = tid & 63;
    const int quad = lane >> 4, l15 = lane & 15;
    const int wm = (wv >> 1) * 64, wn = (wv & 1) * 64;
    const int bm = blockIdx.x, bn = blockIdx.y;

    const int strow = tid >> 3;
    const int sgch = (tid & 7) ^ (strow & 7);
    const bf16* Ag = A + (long)(bm * 128 + strow) * K + sgch * 8;
    const bf16* Bg = Bt + (long)(bn * 128 + strow) * K + sgch * 8;
    const long row32 = (long)32 * K;

    const int rx0 = ((0 + quad) ^ (l15 & 7)) * 8;
    const int rx1 = ((4 + quad) ^ (l15 & 7)) * 8;

    floatx4 acc[4][4] = {};

    for (int k0 = 0; k0 < K; k0 += 64) {
        __syncthreads();
        #pragma unroll
        for (int i = 0; i < 4; i++) {
            g2lds16(Ag + i * row32 + k0, As + i * 2048 + tid * 8);
            g2lds16(Bg + i * row32 + k0, Bs + i * 2048 + tid * 8);
        }
        __syncthreads();
        #pragma unroll
        for (int kk = 0; kk < 2; kk++) {
            const int rx = kk ? rx1 : rx0;
            short8 af[4], bfr[4];
            #pragma unroll
            for (int i = 0; i < 4; i++) af[i] = ld_frag(&As[(wm + i * 16 + l15) * 64 + rx]);
            #pragma unroll
            for (int j = 0; j < 4; j++) bfr[j] = ld_frag(&Bs[(wn + j * 16 + l15) * 64 + rx]);
            #pragma unroll
            for (int i = 0; i < 4; i++)
                #pragma unroll
                for (int j = 0; j < 4; j++)
                    acc[i][j] = mfma16(af[i], bfr[j], acc[i][j]);
        }
    }

    const int tok0 = bm * 128;
    const int seg = tok0 >> 9;          // block fully inside one segment
    const int s0 = tok0 & 511;

    if (bn < 16) {
        // ---- q or k block: rope. pair partner (col^1) sits in lane l15^1 ----
        const bool isq = (bn < 8);
        #pragma unroll
        for (int j = 0; j < 4; j++) {
            int col = bn * 128 + wn + j * 16 + l15;
            int dcol = col & 1023;                   // within q or k
            int h = dcol >> 6, dh = dcol & 63;
            int pr = dh >> 1;
            float invf = __expf(-(float)pr * (9.210340371976184f / 32.0f));
            #pragma unroll
            for (int i = 0; i < 4; i++)
                #pragma unroll
                for (int r = 0; r < 4; r++) {
                    int sl = s0 + wm + i * 16 + quad * 4 + r;   // s within segment
                    float sn, cs;
                    __sincosf((float)sl * invf, &sn, &cs);
                    float v = acc[i][j][r];
                    float px = __shfl_xor(v, 1);
                    float y = (dh & 1) ? (v * cs + px * sn) : (v * cs - px * sn);
                    if (isq) {
                        qbuf[(long)(tok0 + wm + i * 16 + quad * 4 + r) * DIM + dcol] =
                            __float2bfloat16(y * 0.125f);        // fold DH^-0.5 (exact)
                    } else {
                        kpad[(((long)(seg * 16 + h) * JPAD) + PMEMN + sl) * DH + dh] =
                            __float2bfloat16(y);
                    }
                }
        }
    } else {
        // ---- v block: origv fp32 direct + LDS transpose -> vtpad ----
        const int vq = bn - 16;
        #pragma unroll
        for (int j = 0; j < 4; j++) {
            int lc = wn + j * 16 + l15;
            int vcol = vq * 128 + lc;
            int h = vcol >> 6, dh = vcol & 63;
            #pragma unroll
            for (int i = 0; i < 4; i++)
                #pragma unroll
                for (int r = 0; r < 4; r++) {
                    int sl = s0 + wm + i * 16 + quad * 4 + r;
                    origv[((long)(seg * 16 + h) * SEG + sl) * DH + dh] = acc[i][j][r];
                }
        }
        __syncthreads();   // all waves done reading As/Bs
        #pragma unroll
        for (int i = 0; i < 4; i++)
            #pragma unroll
            for (int j = 0; j < 4; j++)
                #pragma unroll
                for (int r = 0; r < 4; r++)
                    SM[(wm + i * 16 + quad * 4 + r) * 136 + wn + j * 16 + l15] =
                        __float2bfloat16(acc[i][j][r]);
        __syncthreads();
        #pragma unroll
        for (int it = 0; it < 8; it++) {
            int cid = it * 256 + tid;
            int orow = cid >> 4;          // local v-col 0..127
            int tch = cid & 15;           // token chunk of 8
            int vcol = vq * 128 + orow;
            int h = vcol >> 6, dh = vcol & 63;
            short8 pk;
            #pragma unroll
            for (int k = 0; k < 8; k++) {
                bf16 t = SM[(tch * 8 + k) * 136 + orow];
                pk[k] = __builtin_bit_cast(short, t);
            }
            *(short8*)&vtpad[(((long)(seg * 16 + h) * DH + dh) * JPAD) + PMEMN + s0 + tch * 8] = pk;
        }
    }
}

// ------------- pmem rows into kpad/vtpad + zero tail pad -------------
__global__ void fill_pmem_pad(const float* __restrict__ pmem, bf16* __restrict__ kpad,
                              bf16* __restrict__ vtpad) {
    int gid = blockIdx.x * 256 + threadIdx.x;
    int dh = gid & 63, j = (gid >> 6) & 15, sh = gid >> 10;
    int h = sh & 15;
    float kv = pmem[((0 * HEADS + h) * PMEMN + j) * DH + dh];
    float vv = pmem[((1 * HEADS + h) * PMEMN + j) * DH + dh];
    kpad[((long)sh * JPAD + j) * DH + dh] = __float2bfloat16(kv);
    vtpad[((long)sh * DH + dh) * JPAD + j] = __float2bfloat16(vv);
    kpad[((long)sh * JPAD + PMEMN + SEG + j) * DH + dh] = __float2bfloat16(0.0f);
    vtpad[((long)sh * DH + dh) * JPAD + PMEMN + SEG + j] = __float2bfloat16(0.0f);
}

// ------- flash attention v3: 1 wave = 32 q rows, NO block barriers in K-loop -------
__global__ __launch_bounds__(256, 3)
void flash_attn(const bf16* __restrict__ qbuf, const bf16* __restrict__ kpad,
                const bf16* __restrict__ vtpad, bf16* __restrict__ attn_out) {
    const int bid = blockIdx.x;
    const int sh = bid & (NSH - 1);
    const int qblk = bid >> 8;
    const int wv = threadIdx.x >> 6;
    const int lane = threadIdx.x & 63;
    const int quad = lane >> 4, l15 = lane & 15;
    const int qr0 = qblk * 128 + wv * 32;
    const int bw = sh >> 4, h = sh & 15;

    __shared__ __align__(16) short pbuf[4][32 * 32];   // per-wave P tile
    short* pb = pbuf[wv];

    const bf16* qr_g0 = qbuf + (long)(bw * SEG + qr0 + l15) * DIM + h * DH;
    const bf16* qr_g1 = qbuf + (long)(bw * SEG + qr0 + 16 + l15) * DIM + h * DH;
    short8 aq[2][2] = {{ld_frag(qr_g0 + quad * 8), ld_frag(qr_g0 + 32 + quad * 8)},
                       {ld_frag(qr_g1 + quad * 8), ld_frag(qr_g1 + 32 + quad * 8)}};

    // ones B-fragment: B[k][0]=1 -> D[:,0] = row-sum of P
    const short bf16one = (short)0x3F80;
    short8 onesB;
    #pragma unroll
    for (int i = 0; i < 8; i++) onesB[i] = (l15 == 0) ? bf16one : (short)0;

    float mrow[2][4];
    floatx4 o[2][4] = {};
    floatx4 lac[2] = {};
    #pragma unroll
    for (int g = 0; g < 2; g++)
        #pragma unroll
        for (int r = 0; r < 4; r++) mrow[g][r] = -1e30f;

    const bf16* kb = kpad + (long)sh * JPAD * DH;
    const bf16* vbp = vtpad + (long)sh * DH * JPAD;

    const int ntiles = (qr0 + 47) / 32 + 1;

    short8 kf[4];
    {
        const bf16* kr0 = kb + (long)l15 * DH;
        const bf16* kr1 = kb + (long)(16 + l15) * DH;
        kf[0] = ld_frag(kr0 + quad * 8);  kf[1] = ld_frag(kr0 + 32 + quad * 8);
        kf[2] = ld_frag(kr1 + quad * 8);  kf[3] = ld_frag(kr1 + 32 + quad * 8);
    }

    for (int jt = 0; jt < ntiles; ++jt) {
        const int j0 = jt * 32;
        short8 bv[4];
        #pragma unroll
        for (int n = 0; n < 4; n++)
            bv[n] = ld_frag(vbp + (long)(n * 16 + l15) * JPAD + j0 + quad * 8);

        floatx4 sc[2][2];
        #pragma unroll
        for (int g = 0; g < 2; g++) {
            sc[g][0] = mfma16(aq[g][1], kf[1], mfma16(aq[g][0], kf[0], floatx4{}));
            sc[g][1] = mfma16(aq[g][1], kf[3], mfma16(aq[g][0], kf[2], floatx4{}));
        }
        {
            const int jn = (jt + 1 < ntiles) ? j0 + 32 : j0;
            const bf16* kr0 = kb + (long)(jn + l15) * DH;
            const bf16* kr1 = kb + (long)(jn + 16 + l15) * DH;
            kf[0] = ld_frag(kr0 + quad * 8);  kf[1] = ld_frag(kr0 + 32 + quad * 8);
            kf[2] = ld_frag(kr1 + quad * 8);  kf[3] = ld_frag(kr1 + 32 + quad * 8);
        }

        float alpha[2][4];
        #pragma unroll
        for (int g = 0; g < 2; g++) {
            #pragma unroll
            for (int r = 0; r < 4; r++) {
                int qi = qr0 + g * 16 + quad * 4 + r;
                int ja = j0 + l15;
                int jb = j0 + 16 + l15;
                float va  = ((ja < PMEMN) || (ja - PMEMN <= qi)) ? sc[g][0][r] : -1e30f;
                float vb2 = ((jb < PMEMN) || (jb - PMEMN <= qi)) ? sc[g][1][r] : -1e30f;
                float rm = fmaxf(va, vb2);
                #pragma unroll
                for (int off = 1; off < 16; off <<= 1) rm = fmaxf(rm, __shfl_xor(rm, off));
                float mn = fmaxf(mrow[g][r], rm);
                alpha[g][r] = __expf(mrow[g][r] - mn);
                mrow[g][r] = mn;
                float p0 = __expf(va - mn);
                float p1 = __expf(vb2 - mn);
                pb[(g * 16 + quad * 4 + r) * 32 + l15]      = __builtin_bit_cast(short, __float2bfloat16(p0));
                pb[(g * 16 + quad * 4 + r) * 32 + 16 + l15] = __builtin_bit_cast(short, __float2bfloat16(p1));
            }
        }
        __asm__ volatile("" ::: "memory");
        short8 pa0, pa1;
        __builtin_memcpy(&pa0, &pb[l15 * 32 + quad * 8], 16);
        __builtin_memcpy(&pa1, &pb[(16 + l15) * 32 + quad * 8], 16);
        __asm__ volatile("" ::: "memory");
        #pragma unroll
        for (int r = 0; r < 4; r++) { lac[0][r] *= alpha[0][r]; lac[1][r] *= alpha[1][r]; }
        lac[0] = mfma16(pa0, onesB, lac[0]);
        lac[1] = mfma16(pa1, onesB, lac[1]);
        #pragma unroll
        for (int n = 0; n < 4; n++) {
            #pragma unroll
            for (int r = 0; r < 4; r++) { o[0][n][r] *= alpha[0][r]; o[1][n][r] *= alpha[1][r]; }
            o[0][n] = mfma16(pa0, bv[n], o[0][n]);
            o[1][n] = mfma16(pa1, bv[n], o[1][n]);
        }
    }
    #pragma unroll
    for (int g = 0; g < 2; g++) {
        bf16* orow = attn_out + (long)(bw * SEG + qr0 + g * 16 + quad * 4) * DIM + h * DH;
        #pragma unroll
        for (int r = 0; r < 4; r++) {
            float lsum = __shfl(lac[g][r], (lane & 48));
            float inv = 1.0f / lsum;
            #pragma unroll
            for (int n = 0; n < 4; n++)
                orow[(long)r * DIM + n * 16 + l15] = __float2bfloat16(o[g][n][r] * inv);
        }
    }
}

extern "C" void kernel_launch(void* const* d_in, const int* in_sizes, int n_in,
                              void* d_out, int out_size, void* d_ws, size_t ws_size,
                              hipStream_t stream) {
    const float* seq    = (const float*)d_in[0];
    const float* norm_w = (const float*)d_in[1];
    const float* w_qkv  = (const float*)d_in[2];
    const float* w_out  = (const float*)d_in[3];
    const float* pmem   = (const float*)d_in[4];
    // Reference outputs are FLOAT32: d_out = [out, orig_v] fp32.
    float* out   = (float*)d_out;
    float* origv = out + (long)TOK * DIM;

    char* p = (char*)d_ws;
    bf16* xn     = (bf16*)p; p += (long)TOK * DIM * 2;
    bf16* wqkvT  = (bf16*)p; p += (long)NQKV * DIM * 2;
    bf16* woutT  = (bf16*)p; p += (long)DIM * DIM * 2;
    bf16* qbuf   = (bf16*)p; p += (long)TOK * DIM * 2;
    bf16* kpadb  = (bf16*)p; p += (long)NSH * JPAD * DH * 2;
    bf16* vtpadb = (bf16*)p; p += (long)NSH * DH * JPAD * 2;
    bf16* attno  = xn;   // xn dead after QKV GEMM

    rmsnorm_kernel<<<TOK, 256, 0, stream>>>(seq, norm_w, xn);
    transpose_w2<<<dim3(128, 32), dim3(32, 8), 0, stream>>>(w_qkv, w_out, wqkvT, woutT);
    fill_pmem_pad<<<(NSH * PMEMN * DH) / 256, 256, 0, stream>>>(pmem, kpadb, vtpadb);
    gemm_qkv_ep<<<dim3(TOK / 128, NQKV / 128), 256, 0, stream>>>(xn, wqkvT, qbuf, kpadb, vtpadb, origv);
    flash_attn<<<4 * NSH, 256, 0, stream>>>(qbuf, kpadb, vtpadb, attno);
    gemm_bt<float><<<dim3(TOK / 128, DIM / 128), 256, 0, stream>>>(attno, woutT, out, TOK, DIM, DIM);
}